// Round 1
// baseline (31432.593 us; speedup 1.0000x reference)
//
#include <hip/hip_runtime.h>
#include <math.h>

// Problem: B=128, T=512, D=64, H=512, 3H=1536
#define TB 512      // threads per block
#define NSLICE 64   // dim slices (8 h-dims each)
#define NGROUP 4    // batch groups (32 batches each)
#define BBATCH 32

// LDS float offsets
#define L_WBUF 0               // 48 rows x 512  (phys 0..23 = Whh r/z/n, 24..39 = Wsum r/z, 40..47 = Wc n)
#define L_WIH  24576           // 24 x 66 (W_ih slice rows r/z/n, 65 cols + pad)
#define L_HL   26160           // 32 x 258 (h stage, [b][k] padded)
#define L_XL   34416           // 32 x 66  (x_t stage incl delta)
#define L_PRE  36528           // 4 x 8 x 33 (r,z,nh,ni preacts)
#define L_ORED 37584           // 32 x 17 (out reduction)
#define L_WOC  38128           // 512 (W_out column s)
#define L_XLAST 38640          // 32
#define L_SB   38672           // 80 small biases
#define LDS_FLOATS 38752
#define LDS_BYTES (LDS_FLOATS * 4)

// ws layout (bytes)
#define H0_OFF 0
#define H1_OFF (128 * 512 * 4)
#define CTR_OFF (2 * 128 * 512 * 4)
#define WS_NEEDED (CTR_OFF + 4096)

__global__ __launch_bounds__(TB) void gru_persistent(
    const float* __restrict__ x, const float* __restrict__ tp, const int* __restrict__ mask,
    const float* __restrict__ W_ih, const float* __restrict__ W_hh,
    const float* __restrict__ b_ih, const float* __restrict__ b_hh,
    const float* __restrict__ W_out, const float* __restrict__ b_out,
    float* __restrict__ hbuf0, float* __restrict__ hbuf1,
    unsigned* __restrict__ ctr, float* __restrict__ out)
{
  extern __shared__ float lds[];
  const int tid = threadIdx.x;
  const int wg  = blockIdx.x;
  const int s   = wg & 63;        // dim slice 0..63 (also the output dim this WG owns)
  const int g   = wg >> 6;        // batch group 0..3
  const int bg0 = g * BBATCH;
  const int j0  = 8 * s;          // first h-dim owned
  const int r2  = tid >> 5;       // 0..15
  const int bb  = tid & 31;       // batch within group

  // ---------------- init: stage weights ----------------
  for (int p = 0; p < 24; ++p) {
    int row = (p < 8) ? (j0 + p) : (p < 16) ? (512 + j0 + (p - 8)) : (1024 + j0 + (p - 16));
    lds[L_WBUF + p * 512 + tid] = W_hh[(size_t)row * 512 + tid];
  }
  if (tid < 65) {
    for (int p = 0; p < 24; ++p) {
      int row = (p < 8) ? (j0 + p) : (p < 16) ? (512 + j0 + (p - 8)) : (1024 + j0 + (p - 16));
      lds[L_WIH + p * 66 + tid] = W_ih[(size_t)row * 65 + tid];
    }
  }
  lds[L_WOC + tid] = W_out[(size_t)tid * 64 + s];
  if (tid < 16) {
    int row = (tid < 8) ? (j0 + tid) : (512 + j0 + (tid - 8));
    const float* wi = W_ih + (size_t)row * 65;
    float bt = b_ih[row] + b_hh[row];
    float bp = 0.f;
    for (int d = 0; d < 64; ++d) bp = fmaf(wi[d], b_out[d], bp);
    lds[L_SB + tid]      = bt;        // teacher bias (r/z)
    lds[L_SB + 16 + tid] = bt + bp;   // AR bias (r/z)
    lds[L_SB + 32 + tid] = wi[64];    // W_ih last col (r/z)
  } else if (tid < 24) {
    int jj = tid - 16;
    int row = 1024 + j0 + jj;
    const float* wi = W_ih + (size_t)row * 65;
    float bp = 0.f;
    for (int d = 0; d < 64; ++d) bp = fmaf(wi[d], b_out[d], bp);
    lds[L_SB + 48 + jj] = b_hh[row];        // nh bias
    lds[L_SB + 56 + jj] = b_ih[row];        // ni bias teacher
    lds[L_SB + 64 + jj] = b_ih[row] + bp;   // ni bias AR
    lds[L_SB + 72 + jj] = wi[64];           // W_ih last col (n)
  }
  if (tid < 256) {
    int b = tid & 31, jj = tid >> 5;
    hbuf0[(size_t)(bg0 + b) * 512 + j0 + jj] = 0.f;   // h0 = 0
  }
  __syncthreads();
  // Fold Wc = W_ih[:, :64] @ W_out^T into LDS: phys 24..39 = Whh+Wc (r,z), 40..47 = Wc (n)
  {
    const float* worow = W_out + (size_t)tid * 64;
    for (int p = 0; p < 24; ++p) {
      const float* wi = &lds[L_WIH + p * 66];
      float acc = 0.f;
#pragma unroll 8
      for (int d = 0; d < 64; ++d) acc = fmaf(wi[d], worow[d], acc);
      float v = (p < 16) ? (lds[L_WBUF + p * 512 + tid] + acc) : acc;
      lds[L_WBUF + (24 + p) * 512 + tid] = v;
    }
  }

  unsigned epoch = 1;
  auto group_barrier = [&](void) {
    __threadfence();
    __syncthreads();
    if (tid == 0) {
      __hip_atomic_fetch_add(&ctr[g * 64], 1u, __ATOMIC_RELAXED, __HIP_MEMORY_SCOPE_AGENT);
      unsigned tgt = 64u * epoch;
      int cnt = 0;
      while (__hip_atomic_load(&ctr[g * 64], __ATOMIC_RELAXED, __HIP_MEMORY_SCOPE_AGENT) < tgt) {
        __builtin_amdgcn_s_sleep(8);
        if (++cnt > 8192) break;   // escape hatch: wrong answer instead of hang
      }
      __threadfence();
    }
    __syncthreads();
    epoch++;
  };

  float* hc = hbuf0;
  float* hn = hbuf1;
  group_barrier();   // h0 zeroing visible group-wide

  for (int t = 0; t <= 512; ++t) {
    const bool last = (t == 512);
    const bool teacher = (!last) && (mask[t] != 0);
    const int phys1 = teacher ? r2 : (24 + r2);
    int phys2;
    if (r2 < 8) phys2 = 16 + r2;                       // nh rows (both modes)
    else        phys2 = teacher ? -1 : (40 + (r2 - 8)); // ni rows (AR only; teacher via x-pass)

    float a1x = 0.f, a1y = 0.f, a2x = 0.f, a2y = 0.f;
    float outacc = 0.f;

    for (int half = 0; half < 2; ++half) {
      __syncthreads();
      {
        const float* hsrc = hc + half * 256;
#pragma unroll
        for (int i = 0; i < 8; ++i) {
          int vid = tid + i * TB;       // 0..4095
          int b = vid >> 7;
          int kv = vid & 127;
          float2 v = *(const float2*)(hsrc + (size_t)(bg0 + b) * 512 + kv * 2);
          *(float2*)&lds[L_HL + b * 258 + kv * 2] = v;
        }
      }
      if (half == 0) {
        if (teacher) {
#pragma unroll
          for (int i = 0; i < 2; ++i) {
            int vid = tid + i * TB;     // 0..1023
            int b = vid >> 5;
            int dv = vid & 31;
            float2 v = *(const float2*)(x + ((size_t)(bg0 + b) * 512 + t) * 64 + dv * 2);
            *(float2*)&lds[L_XL + b * 66 + dv * 2] = v;
          }
          if (tid < 32) {
            size_t ti = (size_t)(bg0 + tid) * 512 + t;
            float d0 = tp[ti] - (t > 0 ? tp[ti - 1] : 0.f);
            lds[L_XL + tid * 66 + 64] = d0;
          }
        } else if (!last) {
          if (tid < 32)
            lds[L_XLAST + tid] = x[((size_t)(bg0 + tid) * 512 + t) * 64 + 63];
        }
      }
      __syncthreads();

      if (!last) {
        const float* w1 = &lds[L_WBUF + phys1 * 512 + half * 256];
        const float* hr = &lds[L_HL + bb * 258];
        if (phys2 >= 0) {
          const float* w2 = &lds[L_WBUF + phys2 * 512 + half * 256];
#pragma unroll 4
          for (int k = 0; k < 256; k += 4) {
            float2 ha = *(const float2*)(hr + k);
            float2 hb = *(const float2*)(hr + k + 2);
            float4 wa = *(const float4*)(w1 + k);
            float4 wb = *(const float4*)(w2 + k);
            a1x = fmaf(wa.x, ha.x, a1x);
            a1y = fmaf(wa.y, ha.y, a1y);
            a1x = fmaf(wa.z, hb.x, a1x);
            a1y = fmaf(wa.w, hb.y, a1y);
            a2x = fmaf(wb.x, ha.x, a2x);
            a2y = fmaf(wb.y, ha.y, a2y);
            a2x = fmaf(wb.z, hb.x, a2x);
            a2y = fmaf(wb.w, hb.y, a2y);
          }
        } else {
#pragma unroll 4
          for (int k = 0; k < 256; k += 4) {
            float2 ha = *(const float2*)(hr + k);
            float2 hb = *(const float2*)(hr + k + 2);
            float4 wa = *(const float4*)(w1 + k);
            a1x = fmaf(wa.x, ha.x, a1x);
            a1y = fmaf(wa.y, ha.y, a1y);
            a1x = fmaf(wa.z, hb.x, a1x);
            a1y = fmaf(wa.w, hb.y, a1y);
          }
        }
      }
      {
        // out partial: out[b][s] over this half's K range
        const float* hr2 = &lds[L_HL + bb * 258 + r2 * 16];
        const float* wc  = &lds[L_WOC + half * 256 + r2 * 16];
#pragma unroll
        for (int kk = 0; kk < 16; ++kk) outacc = fmaf(hr2[kk], wc[kk], outacc);
      }
    } // halves

    if (!last) {
      float xlv = teacher ? 0.f : lds[L_XLAST + bb];
      if (teacher) {
        const float* xr  = &lds[L_XL + bb * 66];
        const float* wi1 = &lds[L_WIH + r2 * 66];
        float xa = 0.f;
#pragma unroll
        for (int kx = 0; kx < 65; ++kx) xa = fmaf(wi1[kx], xr[kx], xa);
        a1x += xa;
        if (r2 >= 8) {
          const float* wi2 = &lds[L_WIH + (r2 + 8) * 66];
          float xb = 0.f;
#pragma unroll
          for (int kx = 0; kx < 65; ++kx) xb = fmaf(wi2[kx], xr[kx], xb);
          a2x += xb;
        }
      }
      float acc1 = a1x + a1y;
      float acc2 = a2x + a2y;
      acc1 += teacher ? lds[L_SB + r2] : (lds[L_SB + 16 + r2] + lds[L_SB + 32 + r2] * xlv);
      if (r2 < 8) acc2 += lds[L_SB + 48 + r2];
      else {
        int jj = r2 - 8;
        acc2 += teacher ? lds[L_SB + 56 + jj] : (lds[L_SB + 64 + jj] + lds[L_SB + 72 + jj] * xlv);
      }
      int p1 = (r2 < 8) ? (0 * 8 + r2) : (1 * 8 + (r2 - 8));
      int p2 = (r2 < 8) ? (2 * 8 + r2) : (3 * 8 + (r2 - 8));
      lds[L_PRE + p1 * 33 + bb] = acc1;
      lds[L_PRE + p2 * 33 + bb] = acc2;
    }
    lds[L_ORED + bb * 17 + r2] = outacc;
    __syncthreads();

    if (t >= 1 && tid < 32) {
      float o = 0.f;
#pragma unroll
      for (int i = 0; i < 16; ++i) o += lds[L_ORED + tid * 17 + i];
      o += b_out[s];
      out[((size_t)(bg0 + tid) * 512 + (t - 1)) * 64 + s] = o;
    }
    if (!last) {
      if (tid < 256) {
        int b = tid & 31, jj = tid >> 5;
        float pr = lds[L_PRE + (0 * 8 + jj) * 33 + b];
        float pz = lds[L_PRE + (1 * 8 + jj) * 33 + b];
        float ph = lds[L_PRE + (2 * 8 + jj) * 33 + b];
        float pn = lds[L_PRE + (3 * 8 + jj) * 33 + b];
        float rg = 1.f / (1.f + expf(-pr));
        float zg = 1.f / (1.f + expf(-pz));
        float ng = tanhf(fmaf(rg, ph, pn));
        float hp = hc[(size_t)(bg0 + b) * 512 + j0 + jj];
        float hv = fmaf(zg, hp - ng, ng);   // (1-z)*n + z*h
        hn[(size_t)(bg0 + b) * 512 + j0 + jj] = hv;
      }
      group_barrier();
      float* tswap = hc; hc = hn; hn = tswap;
    }
  }
}

extern "C" void kernel_launch(void* const* d_in, const int* in_sizes, int n_in,
                              void* d_out, int out_size, void* d_ws, size_t ws_size,
                              hipStream_t stream) {
  (void)in_sizes; (void)n_in; (void)out_size;
  const float* x    = (const float*)d_in[0];
  const float* tp   = (const float*)d_in[1];
  const int*   mask = (const int*)d_in[2];
  const float* W_ih = (const float*)d_in[3];
  const float* W_hh = (const float*)d_in[4];
  const float* b_ih = (const float*)d_in[5];
  const float* b_hh = (const float*)d_in[6];
  const float* W_out= (const float*)d_in[7];
  const float* b_out= (const float*)d_in[8];
  float* out = (float*)d_out;
  if (ws_size < (size_t)WS_NEEDED) return;
  char* ws = (char*)d_ws;
  float* h0 = (float*)(ws + H0_OFF);
  float* h1 = (float*)(ws + H1_OFF);
  unsigned* ctr = (unsigned*)(ws + CTR_OFF);
  hipMemsetAsync(ctr, 0, 4096, stream);
  hipFuncSetAttribute((const void*)gru_persistent,
                      hipFuncAttributeMaxDynamicSharedMemorySize, LDS_BYTES);
  hipLaunchKernelGGL(gru_persistent, dim3(NSLICE * NGROUP), dim3(TB), LDS_BYTES, stream,
                     x, tp, mask, W_ih, W_hh, b_ih, b_hh, W_out, b_out, h0, h1, ctr, out);
}

// Round 3
// 27850.854 us; speedup vs baseline: 1.1286x; 1.1286x over previous
//
#include <hip/hip_runtime.h>
#include <math.h>

// B=128, T=512, D=64, H=512. Grid: 64 dim-slices (8 h-dims each) x 4 batch-groups (32 batches).
// Gates via split-bf16 MFMA (3-term): PRE = h @ W^T with W in LDS as bf16 hi/lo B-fragments.
// h exchanged via global bf16 hi/lo planes in MFMA-fragment-linear-compatible layout.
#define TB 512

typedef __attribute__((ext_vector_type(8))) short bf16x8;
typedef __attribute__((ext_vector_type(4))) float f32x4;

// LDS layout. Byte offsets for frag regions, float offsets for f32 regions.
#define BW_B   0        // 3 ct x 2 term x 16 ks x 1024B = 98304  (weight B-frags)
#define AH_B   98304    // 2 term x 16 ks x 1024B = 32768         (h A-frags, one batch-half)
#define PRE_F  32768    // f32[32][33]  (gate preacts: rows 0-15 mode rz, 16-23 nh, 24-31 ni)
#define XPRE_F 33824    // f32[24][33]  (teacher x-dot: r8,z8,n8)
#define ORED_F 34616    // f32[32][17]  (out partials)
#define WOC_F  35160    // f32[512]     (W_out column s)
#define WIH_F  35672    // f32[24][66]  (W_ih slice rows)
#define SB_F   37256    // f32[96]      (biases; [80]=b_out[s])
#define HST_F  37352    // f32[32][9]   (new h staging)
#define XD_F   37640    // f32[32]      (delta_t)
#define XLAST_F 37672   // f32[32]      (x last channel, AR)
#define LDS_BYTES 150816

#define PLANE_STRIDE 262144   // bytes per (HH,HL) plane pair
#define CTR_OFF 524288
#define WS_NEEDED (CTR_OFF + 4096)

__device__ __forceinline__ unsigned rne16(float f) {
  unsigned u = __float_as_uint(f);
  return (u + 0x7FFFu + ((u >> 16) & 1u)) >> 16;
}
__device__ __forceinline__ float bfhilo(unsigned hh, unsigned hl) {
  return __uint_as_float(hh << 16) + __uint_as_float(hl << 16);
}

__global__ __launch_bounds__(TB) void gru_persistent(
    const float* __restrict__ x, const float* __restrict__ tp, const int* __restrict__ mask,
    const float* __restrict__ W_ih, const float* __restrict__ W_hh,
    const float* __restrict__ b_ih, const float* __restrict__ b_hh,
    const float* __restrict__ W_out, const float* __restrict__ b_out,
    unsigned short* __restrict__ planes, unsigned* __restrict__ ctr,
    float* __restrict__ out)
{
  extern __shared__ char smem[];
  float* LP = (float*)smem;
  const int tid = threadIdx.x;
  const int wg  = blockIdx.x;
  const int s   = wg & 63;
  const int g   = wg >> 6;
  const int bg0 = g * 32;
  const int j0  = 8 * s;
  const int lane = tid & 63;
  const int wv   = tid >> 6;

  // ---------------- init ----------------
  if (tid < 65) {
    for (int p = 0; p < 24; ++p) {
      int row = (p < 8) ? (j0 + p) : (p < 16) ? (512 + j0 + (p - 8)) : (1024 + j0 + (p - 16));
      LP[WIH_F + p * 66 + tid] = W_ih[(size_t)row * 65 + tid];
    }
  }
  LP[WOC_F + tid] = W_out[(size_t)tid * 64 + s];
  if (tid < 16) {
    int row = (tid < 8) ? (j0 + tid) : (512 + j0 + (tid - 8));
    const float* wi = W_ih + (size_t)row * 65;
    float bt = b_ih[row] + b_hh[row];
    float bp = 0.f;
    for (int d = 0; d < 64; ++d) bp = fmaf(wi[d], b_out[d], bp);
    LP[SB_F + tid]      = bt;        // teacher rz bias
    LP[SB_F + 16 + tid] = bt + bp;   // AR rz bias
    LP[SB_F + 32 + tid] = wi[64];    // xlast coef rz
  } else if (tid < 24) {
    int jj = tid - 16;
    int row = 1024 + j0 + jj;
    const float* wi = W_ih + (size_t)row * 65;
    float bp = 0.f;
    for (int d = 0; d < 64; ++d) bp = fmaf(wi[d], b_out[d], bp);
    LP[SB_F + 48 + jj] = b_hh[row];
    LP[SB_F + 56 + jj] = b_ih[row];
    LP[SB_F + 64 + jj] = b_ih[row] + bp;
    LP[SB_F + 72 + jj] = wi[64];
  }
  if (tid == 0) LP[SB_F + 80] = b_out[s];
  // zero h0 planes (sel 0)
  if (tid < 32) {
    uint4 z = {0, 0, 0, 0};
    unsigned short* hh0 = planes;
    unsigned short* hl0 = planes + 65536;
    *(uint4*)(hh0 + (size_t)(bg0 + tid) * 512 + j0) = z;
    *(uint4*)(hl0 + (size_t)(bg0 + tid) * 512 + j0) = z;
  }
  __syncthreads();

  // build weight B-frags (split bf16). thread = k.
  {
    const int k = tid;
    const float* wo = W_out + (size_t)k * 64;
    unsigned short* bw16 = (unsigned short*)(smem + BW_B);
    for (int rr = 0; rr < 48; ++rr) {
      int c, col; float w;
      if (rr < 16) {
        c = 1; col = rr;
        int row = (rr < 8) ? (j0 + rr) : (512 + j0 + rr - 8);
        w = W_hh[(size_t)row * 512 + k];
      } else if (rr < 24) {
        c = 0; col = rr - 16;
        w = W_hh[(size_t)(1024 + j0 + rr - 16) * 512 + k];
      } else {
        int p, whrow;
        if (rr < 32) { c = 0; col = rr - 24 + 8; p = 16 + (rr - 24); whrow = -1; }
        else if (rr < 40) { c = 2; col = rr - 32; p = rr - 32; whrow = j0 + rr - 32; }
        else { c = 2; col = rr - 40 + 8; p = 8 + (rr - 40); whrow = 512 + j0 + rr - 40; }
        const float* wr = &LP[WIH_F + p * 66];
        float a = 0.f;
#pragma unroll 8
        for (int d = 0; d < 64; ++d) a = fmaf(wr[d], wo[d], a);
        w = a + (whrow >= 0 ? W_hh[(size_t)whrow * 512 + k] : 0.f);
      }
      unsigned wh = rne16(w);
      float resid = w - __uint_as_float(wh << 16);
      unsigned wl = rne16(resid);
      int base = c * 32768 + (k >> 5) * 1024 + (col | (((k >> 3) & 3) << 4)) * 16 + (k & 7) * 2;
      bw16[base >> 1] = (unsigned short)wh;
      bw16[(base + 16384) >> 1] = (unsigned short)wl;
    }
  }
  __syncthreads();

  unsigned epoch = 1;
  auto group_barrier = [&](void) {
    __threadfence();
    __syncthreads();
    if (tid == 0) {
      __hip_atomic_fetch_add(&ctr[g * 64], 1u, __ATOMIC_RELAXED, __HIP_MEMORY_SCOPE_AGENT);
      unsigned tgt = 64u * epoch;
      int cnt = 0;
      while (__hip_atomic_load(&ctr[g * 64], __ATOMIC_RELAXED, __HIP_MEMORY_SCOPE_AGENT) < tgt) {
        __builtin_amdgcn_s_sleep(4);
        if (++cnt > 131072) break;   // escape hatch
      }
      __threadfence();
    }
    __syncthreads();
    epoch++;
  };

  group_barrier();   // h0 planes visible group-wide

  const unsigned short* ah16 = (const unsigned short*)(smem + AH_B);

  for (int t = 0; t <= 512; ++t) {
    const bool last = (t == 512);
    const bool teacher = (!last) && (mask[t] != 0);
    const int csel = teacher ? 1 : 2;
    const int cur = t & 1;
    const unsigned short* HHc = planes + (size_t)cur * (PLANE_STRIDE / 2);
    const unsigned short* HLc = HHc + 65536;
    unsigned short* HHn = (unsigned short*)(planes + (size_t)(cur ^ 1) * (PLANE_STRIDE / 2));
    unsigned short* HLn = HHn + 65536;

    // -------- phase A: issue both halves' loads; write half0 frags --------
    uint4 stg0[4], stg1[4];
#pragma unroll
    for (int i = 0; i < 4; ++i) {
      int c = i * 512 + tid;          // chunk id 0..2047
      int sg = c >> 6, ln = c & 63;
      int term = sg >> 4, ks = sg & 15;
      const unsigned short* pl = term ? HLc : HHc;
      const unsigned short* src0 = pl + ((size_t)(bg0 + (ln & 15)) * 512 + ks * 32 + ((ln >> 4) & 3) * 8);
      stg0[i] = *(const uint4*)src0;
      stg1[i] = *(const uint4*)(src0 + 16 * 512);
    }
    if (!last && tid < 32) {
      if (teacher) {
        size_t ti = (size_t)(bg0 + tid) * 512 + t;
        LP[XD_F + tid] = tp[ti] - (t > 0 ? tp[ti - 1] : 0.f);
      } else {
        LP[XLAST_F + tid] = x[((size_t)(bg0 + tid) * 512 + t) * 64 + 63];
      }
    }
#pragma unroll
    for (int i = 0; i < 4; ++i) {
      int c = i * 512 + tid;
      *(uint4*)(smem + AH_B + c * 16) = stg0[i];
    }
    __syncthreads();

    float hp = 0.f;
    for (int half = 0; half < 2; ++half) {
      const int rtoff = half * 16;

      // MFMA waves: wv0 -> ct0 (nh+ni), wv1 -> mode ct
      if (!last && wv < 2) {
        const int cslot = (wv == 0) ? 0 : csel;
        const char* bb = smem + BW_B + cslot * 32768;
        const char* ab = smem + AH_B;
        f32x4 acc0 = {0.f, 0.f, 0.f, 0.f};
        f32x4 acc1 = {0.f, 0.f, 0.f, 0.f};
        f32x4 acc2 = {0.f, 0.f, 0.f, 0.f};
        f32x4 acc3 = {0.f, 0.f, 0.f, 0.f};
#pragma unroll
        for (int ks4 = 0; ks4 < 4; ++ks4) {
#pragma unroll
          for (int q4 = 0; q4 < 4; ++q4) {
            int ks = ks4 * 4 + q4;
            bf16x8 ahh = *(const bf16x8*)(ab + ks * 1024 + lane * 16);
            bf16x8 ahl = *(const bf16x8*)(ab + (16 + ks) * 1024 + lane * 16);
            bf16x8 bhh = *(const bf16x8*)(bb + ks * 1024 + lane * 16);
            bf16x8 bhl = *(const bf16x8*)(bb + (16 + ks) * 1024 + lane * 16);
            f32x4& acc = (q4 == 0) ? acc0 : (q4 == 1) ? acc1 : (q4 == 2) ? acc2 : acc3;
            acc = __builtin_amdgcn_mfma_f32_16x16x32_bf16(ahh, bhh, acc, 0, 0, 0);
            acc = __builtin_amdgcn_mfma_f32_16x16x32_bf16(ahh, bhl, acc, 0, 0, 0);
            acc = __builtin_amdgcn_mfma_f32_16x16x32_bf16(ahl, bhh, acc, 0, 0, 0);
          }
        }
        f32x4 accA = acc0 + acc1;
        f32x4 accB = acc2 + acc3;
        f32x4 acc = accA + accB;
        const int prow = ((wv == 0) ? 16 : 0) + (lane & 15);
        const int pcol = rtoff + ((lane >> 4) << 2);
#pragma unroll
        for (int q = 0; q < 4; ++q) LP[PRE_F + prow * 33 + pcol + q] = acc[q];
      }

      // out-dot: 256 tasks (16 local batches x 16 ks)
      if (tid >= 128 && tid < 384) {
        const int tA = tid - 128;
        const int bl = tA & 15, ks = tA >> 4;
        const int b = rtoff + bl;
        const float* woc = &LP[WOC_F];
        float oa = 0.f;
#pragma unroll
        for (int c = 0; c < 4; ++c) {
          const uint4 wh = *(const uint4*)(smem + AH_B + ks * 1024 + (bl | (c << 4)) * 16);
          const uint4 wl = *(const uint4*)(smem + AH_B + (16 + ks) * 1024 + (bl | (c << 4)) * 16);
          int k0 = ks * 32 + c * 8;
          oa = fmaf(bfhilo(wh.x & 0xFFFFu, wl.x & 0xFFFFu), woc[k0 + 0], oa);
          oa = fmaf(bfhilo(wh.x >> 16, wl.x >> 16), woc[k0 + 1], oa);
          oa = fmaf(bfhilo(wh.y & 0xFFFFu, wl.y & 0xFFFFu), woc[k0 + 2], oa);
          oa = fmaf(bfhilo(wh.y >> 16, wl.y >> 16), woc[k0 + 3], oa);
          oa = fmaf(bfhilo(wh.z & 0xFFFFu, wl.z & 0xFFFFu), woc[k0 + 4], oa);
          oa = fmaf(bfhilo(wh.z >> 16, wl.z >> 16), woc[k0 + 5], oa);
          oa = fmaf(bfhilo(wh.w & 0xFFFFu, wl.w & 0xFFFFu), woc[k0 + 6], oa);
          oa = fmaf(bfhilo(wh.w >> 16, wl.w >> 16), woc[k0 + 7], oa);
        }
        LP[ORED_F + b * 17 + ks] = oa;
      }

      // teacher x-dot: 384 tasks (24 rows x 16 local batches)
      if (teacher && tid >= 128) {
        const int t2 = tid - 128;
        if (t2 < 384) {
          const int xr = t2 >> 4;
          const int b = rtoff + (t2 & 15);
          const float* wrow = &LP[WIH_F + xr * 66];
          float xa = wrow[64] * LP[XD_F + b];
          const float4* x4 = (const float4*)(x + ((size_t)(bg0 + b) * 512 + t) * 64);
#pragma unroll
          for (int d4 = 0; d4 < 16; ++d4) {
            float4 xv = x4[d4];
            xa = fmaf(wrow[d4 * 4 + 0], xv.x, xa);
            xa = fmaf(wrow[d4 * 4 + 1], xv.y, xa);
            xa = fmaf(wrow[d4 * 4 + 2], xv.z, xa);
            xa = fmaf(wrow[d4 * 4 + 3], xv.w, xa);
          }
          LP[XPRE_F + xr * 33 + b] = xa;
        }
      }

      // hp stash for gate threads whose batch is in this half
      if (tid < 256 && (((tid & 31) >> 4) == half)) {
        const int b = tid & 31, jj = tid >> 5;
        const int k = j0 + jj;
        const int ks = k >> 5, e = k & 7;
        const int ln = (b & 15) | (((k >> 3) & 3) << 4);
        unsigned hh = ah16[(ks * 1024 + ln * 16 + e * 2) >> 1];
        unsigned hl = ah16[((16 + ks) * 1024 + ln * 16 + e * 2) >> 1];
        hp = bfhilo(hh, hl);
      }
      __syncthreads();
      if (half == 0) {
#pragma unroll
        for (int i = 0; i < 4; ++i) {
          int c = i * 512 + tid;
          *(uint4*)(smem + AH_B + c * 16) = stg1[i];
        }
        __syncthreads();
      }
    }

    // -------- phase C: gates + out reduce --------
    if (!last && tid < 256) {
      const int b = tid & 31, jj = tid >> 5;
      float pr = LP[PRE_F + jj * 33 + b];
      float pz = LP[PRE_F + (8 + jj) * 33 + b];
      float pnh = LP[PRE_F + (16 + jj) * 33 + b] + LP[SB_F + 48 + jj];
      float pni;
      if (teacher) {
        pr += LP[XPRE_F + jj * 33 + b] + LP[SB_F + jj];
        pz += LP[XPRE_F + (8 + jj) * 33 + b] + LP[SB_F + 8 + jj];
        pni = LP[XPRE_F + (16 + jj) * 33 + b] + LP[SB_F + 56 + jj];
      } else {
        float xl = LP[XLAST_F + b];
        pr += LP[SB_F + 16 + jj] + LP[SB_F + 32 + jj] * xl;
        pz += LP[SB_F + 24 + jj] + LP[SB_F + 40 + jj] * xl;
        pni = LP[PRE_F + (24 + jj) * 33 + b] + LP[SB_F + 64 + jj] + LP[SB_F + 72 + jj] * xl;
      }
      float rg = 1.f / (1.f + expf(-pr));
      float zg = 1.f / (1.f + expf(-pz));
      float ng = tanhf(fmaf(rg, pnh, pni));
      LP[HST_F + b * 9 + jj] = fmaf(zg, hp - ng, ng);
    }
    if (t >= 1 && tid >= 256 && tid < 288) {
      const int b = tid - 256;
      float o = LP[SB_F + 80];
#pragma unroll
      for (int i = 0; i < 16; ++i) o += LP[ORED_F + b * 17 + i];
      out[((size_t)(bg0 + b) * 512 + (t - 1)) * 64 + s] = o;
    }
    __syncthreads();

    // -------- phase D: pack + publish new h --------
    if (!last) {
      if (tid < 32) {
        const int b = tid;
        unsigned hw[4], lw[4];
#pragma unroll
        for (int p = 0; p < 4; ++p) {
          float h0 = LP[HST_F + b * 9 + 2 * p];
          float h1 = LP[HST_F + b * 9 + 2 * p + 1];
          unsigned h0h = rne16(h0), h1h = rne16(h1);
          float r0 = h0 - __uint_as_float(h0h << 16);
          float r1 = h1 - __uint_as_float(h1h << 16);
          hw[p] = h0h | (h1h << 16);
          lw[p] = rne16(r0) | (rne16(r1) << 16);
        }
        uint4 HWv = {hw[0], hw[1], hw[2], hw[3]};
        uint4 LWv = {lw[0], lw[1], lw[2], lw[3]};
        *(uint4*)(HHn + (size_t)(bg0 + b) * 512 + j0) = HWv;
        *(uint4*)(HLn + (size_t)(bg0 + b) * 512 + j0) = LWv;
      }
      group_barrier();
    }
  }
}

extern "C" void kernel_launch(void* const* d_in, const int* in_sizes, int n_in,
                              void* d_out, int out_size, void* d_ws, size_t ws_size,
                              hipStream_t stream) {
  (void)in_sizes; (void)n_in; (void)out_size;
  const float* x    = (const float*)d_in[0];
  const float* tp   = (const float*)d_in[1];
  const int*   mask = (const int*)d_in[2];
  const float* W_ih = (const float*)d_in[3];
  const float* W_hh = (const float*)d_in[4];
  const float* b_ih = (const float*)d_in[5];
  const float* b_hh = (const float*)d_in[6];
  const float* W_out= (const float*)d_in[7];
  const float* b_out= (const float*)d_in[8];
  float* out = (float*)d_out;
  if (ws_size < (size_t)WS_NEEDED) return;
  unsigned short* planes = (unsigned short*)d_ws;
  unsigned* ctr = (unsigned*)((char*)d_ws + CTR_OFF);
  hipMemsetAsync(ctr, 0, 4096, stream);
  hipFuncSetAttribute((const void*)gru_persistent,
                      hipFuncAttributeMaxDynamicSharedMemorySize, LDS_BYTES);
  hipLaunchKernelGGL(gru_persistent, dim3(256), dim3(TB), LDS_BYTES, stream,
                     x, tp, mask, W_ih, W_hh, b_ih, b_hh, W_out, b_out, planes, ctr, out);
}

// Round 4
// 5516.357 us; speedup vs baseline: 5.6981x; 5.0488x over previous
//
#include <hip/hip_runtime.h>
#include <math.h>

// B=128, T=512, D=64, H=512. Grid: 64 dim-slices (8 h-dims each) x 4 batch-groups (32 batches).
// Gates via split-bf16 MFMA (3-term). h exchanged via per-access agent-scope (sc1) atomics;
// NO __threadfence (no L2 writeback/invalidate storms). Barrier = relaxed add + relaxed spin,
// ordered by per-wave vmcnt(0). Teacher x-dot precomputed for t+1 inside the spin window.
#define TB 512

typedef __attribute__((ext_vector_type(8))) short bf16x8;
typedef __attribute__((ext_vector_type(4))) float f32x4;
typedef unsigned long long u64;

// LDS layout. Byte offsets for frag regions, float offsets for f32 regions.
#define BW_B   0        // 3 ct x 2 term x 16 ks x 1024B = 98304  (weight B-frags)
#define AH_B   98304    // 2 term x 16 ks x 1024B = 32768         (h A-frags, one batch-half)
#define PRE_F  32768    // f32[32][33]  (gate preacts: rows 0-15 mode rz, 16-23 nh, 24-31 ni)
#define XPRE_F 33824    // f32[24][33]  (teacher x-dot: r8,z8,n8)
#define ORED_F 34616    // f32[32][17]  (out partials)
#define WOC_F  35160    // f32[512]     (W_out column s)
#define WIH_F  35672    // f32[24][66]  (W_ih slice rows)
#define SB_F   37256    // f32[96]      (biases; [80]=b_out[s])
#define XLAST_F 37352   // f32[32]      (x last channel, AR)
#define MSK_F  37384    // int[512]     (samp mask staged)
#define LDS_FLOATS 37896
#define LDS_BYTES (LDS_FLOATS * 4)   // 151584

#define PLANE_STRIDE 262144   // bytes per (HH,HL) plane pair
#define CTR_OFF 524288
#define WS_NEEDED (CTR_OFF + 4096)

__device__ __forceinline__ unsigned rne16(float f) {
  unsigned u = __float_as_uint(f);
  return (u + 0x7FFFu + ((u >> 16) & 1u)) >> 16;
}
__device__ __forceinline__ float bfhilo(unsigned hh, unsigned hl) {
  return __uint_as_float(hh << 16) + __uint_as_float(hl << 16);
}

__global__ __launch_bounds__(TB) void gru_persistent(
    const float* __restrict__ x, const float* __restrict__ tp, const int* __restrict__ mask,
    const float* __restrict__ W_ih, const float* __restrict__ W_hh,
    const float* __restrict__ b_ih, const float* __restrict__ b_hh,
    const float* __restrict__ W_out, const float* __restrict__ b_out,
    unsigned short* __restrict__ planes, unsigned* __restrict__ ctr,
    float* __restrict__ out)
{
  extern __shared__ char smem[];
  float* LP = (float*)smem;
  int* MSK = (int*)&LP[MSK_F];
  const int tid = threadIdx.x;
  const int wg  = blockIdx.x;
  const int s   = wg & 63;
  const int g   = wg >> 6;
  const int bg0 = g * 32;
  const int j0  = 8 * s;
  const int lane = tid & 63;
  const int wv   = tid >> 6;

  // ---------------- init ----------------
  MSK[tid] = mask[tid];
  if (tid < 65) {
    for (int p = 0; p < 24; ++p) {
      int row = (p < 8) ? (j0 + p) : (p < 16) ? (512 + j0 + (p - 8)) : (1024 + j0 + (p - 16));
      LP[WIH_F + p * 66 + tid] = W_ih[(size_t)row * 65 + tid];
    }
  }
  LP[WOC_F + tid] = W_out[(size_t)tid * 64 + s];
  if (tid < 16) {
    int row = (tid < 8) ? (j0 + tid) : (512 + j0 + (tid - 8));
    const float* wi = W_ih + (size_t)row * 65;
    float bt = b_ih[row] + b_hh[row];
    float bp = 0.f;
    for (int d = 0; d < 64; ++d) bp = fmaf(wi[d], b_out[d], bp);
    LP[SB_F + tid]      = bt;        // teacher rz bias
    LP[SB_F + 16 + tid] = bt + bp;   // AR rz bias
    LP[SB_F + 32 + tid] = wi[64];    // xlast coef rz
  } else if (tid < 24) {
    int jj = tid - 16;
    int row = 1024 + j0 + jj;
    const float* wi = W_ih + (size_t)row * 65;
    float bp = 0.f;
    for (int d = 0; d < 64; ++d) bp = fmaf(wi[d], b_out[d], bp);
    LP[SB_F + 48 + jj] = b_hh[row];
    LP[SB_F + 56 + jj] = b_ih[row];
    LP[SB_F + 64 + jj] = b_ih[row] + bp;
    LP[SB_F + 72 + jj] = wi[64];
  }
  if (tid == 0) LP[SB_F + 80] = b_out[s];
  // zero h0 planes (buffer 0) with sc1 stores (visible at coherence point, no fence needed)
  if (tid < 32) {
    u64* hh0 = (u64*)(planes + (size_t)(bg0 + tid) * 512 + j0);
    u64* hl0 = (u64*)(planes + 65536 + (size_t)(bg0 + tid) * 512 + j0);
    __hip_atomic_store(hh0, 0ull, __ATOMIC_RELAXED, __HIP_MEMORY_SCOPE_AGENT);
    __hip_atomic_store(hh0 + 1, 0ull, __ATOMIC_RELAXED, __HIP_MEMORY_SCOPE_AGENT);
    __hip_atomic_store(hl0, 0ull, __ATOMIC_RELAXED, __HIP_MEMORY_SCOPE_AGENT);
    __hip_atomic_store(hl0 + 1, 0ull, __ATOMIC_RELAXED, __HIP_MEMORY_SCOPE_AGENT);
  }
  __syncthreads();

  // build weight B-frags (split bf16). thread = k.
  {
    const int k = tid;
    const float* wo = W_out + (size_t)k * 64;
    unsigned short* bw16 = (unsigned short*)(smem + BW_B);
    for (int rr = 0; rr < 48; ++rr) {
      int c, col; float w;
      if (rr < 16) {
        c = 1; col = rr;
        int row = (rr < 8) ? (j0 + rr) : (512 + j0 + rr - 8);
        w = W_hh[(size_t)row * 512 + k];
      } else if (rr < 24) {
        c = 0; col = rr - 16;
        w = W_hh[(size_t)(1024 + j0 + rr - 16) * 512 + k];
      } else {
        int p, whrow;
        if (rr < 32) { c = 0; col = rr - 24 + 8; p = 16 + (rr - 24); whrow = -1; }
        else if (rr < 40) { c = 2; col = rr - 32; p = rr - 32; whrow = j0 + rr - 32; }
        else { c = 2; col = rr - 40 + 8; p = 8 + (rr - 40); whrow = 512 + j0 + rr - 40; }
        const float* wr = &LP[WIH_F + p * 66];
        float a = 0.f;
#pragma unroll 8
        for (int d = 0; d < 64; ++d) a = fmaf(wr[d], wo[d], a);
        w = a + (whrow >= 0 ? W_hh[(size_t)whrow * 512 + k] : 0.f);
      }
      unsigned wh = rne16(w);
      float resid = w - __uint_as_float(wh << 16);
      unsigned wl = rne16(resid);
      int base = c * 32768 + (k >> 5) * 1024 + (col | (((k >> 3) & 3) << 4)) * 16 + (k & 7) * 2;
      bw16[base >> 1] = (unsigned short)wh;
      bw16[(base + 16384) >> 1] = (unsigned short)wl;
    }
  }
  __syncthreads();

  // teacher x-dot staging for step tt (h-independent; runs in spin windows)
  auto stage_x = [&](int tt) {
    if (tt >= 512) return;
    if (MSK[tt] != 0) {
      for (int task = tid; task < 768; task += TB) {
        const int xr = task >> 5, b = task & 31;
        const float* wrow = &LP[WIH_F + xr * 66];
        size_t ti = (size_t)(bg0 + b) * 512 + tt;
        float del = tp[ti] - (tt > 0 ? tp[ti - 1] : 0.f);
        float xa = wrow[64] * del;
        const float4* x4 = (const float4*)(x + ti * 64);
#pragma unroll
        for (int d4 = 0; d4 < 16; ++d4) {
          float4 xv = x4[d4];
          xa = fmaf(wrow[d4 * 4 + 0], xv.x, xa);
          xa = fmaf(wrow[d4 * 4 + 1], xv.y, xa);
          xa = fmaf(wrow[d4 * 4 + 2], xv.z, xa);
          xa = fmaf(wrow[d4 * 4 + 3], xv.w, xa);
        }
        LP[XPRE_F + xr * 33 + b] = xa;
      }
    } else if (tid < 32) {
      LP[XLAST_F + tid] = x[((size_t)(bg0 + tid) * 512 + tt) * 64 + 63];
    }
  };

  stage_x(0);

  unsigned target = 64;
  unsigned* myctr = &ctr[g * 64];

  // initial barrier: h0 zeros + stage_x(0) done
  asm volatile("s_waitcnt vmcnt(0)" ::: "memory");
  __syncthreads();
  if (tid == 0) {
    __hip_atomic_fetch_add(myctr, 1u, __ATOMIC_RELAXED, __HIP_MEMORY_SCOPE_AGENT);
    int cnt = 0;
    while (__hip_atomic_load(myctr, __ATOMIC_RELAXED, __HIP_MEMORY_SCOPE_AGENT) < target) {
      __builtin_amdgcn_s_sleep(2);
      if (++cnt > 16384) break;
    }
  }
  __syncthreads();
  target += 64;

  const unsigned short* ah16 = (const unsigned short*)(smem + AH_B);

  for (int t = 0; t <= 512; ++t) {
    const bool last = (t == 512);
    const bool teacher = (!last) && (MSK[t] != 0);
    const int csel = teacher ? 1 : 2;
    const int cur = t & 1;
    const unsigned short* HHc = planes + (size_t)cur * (PLANE_STRIDE / 2);
    const unsigned short* HLc = HHc + 65536;
    unsigned short* HHn = (unsigned short*)(planes + (size_t)(cur ^ 1) * (PLANE_STRIDE / 2));
    unsigned short* HLn = HHn + 65536;

    // -------- phase A: sc1-read both batch-halves of h; write half0 frags --------
    u64 s0a[4], s0b[4], s1a[4], s1b[4];
#pragma unroll
    for (int i = 0; i < 4; ++i) {
      int c = i * 512 + tid;          // chunk id 0..2047
      int sg = c >> 6, ln = c & 63;
      int term = sg >> 4, ks = sg & 15;
      const unsigned short* pl = term ? HLc : HHc;
      const unsigned short* src0 = pl + ((size_t)(bg0 + (ln & 15)) * 512 + ks * 32 + ((ln >> 4) & 3) * 8);
      const u64* p0 = (const u64*)src0;
      const u64* p1 = (const u64*)(src0 + 16 * 512);
      s0a[i] = __hip_atomic_load(p0,     __ATOMIC_RELAXED, __HIP_MEMORY_SCOPE_AGENT);
      s0b[i] = __hip_atomic_load(p0 + 1, __ATOMIC_RELAXED, __HIP_MEMORY_SCOPE_AGENT);
      s1a[i] = __hip_atomic_load(p1,     __ATOMIC_RELAXED, __HIP_MEMORY_SCOPE_AGENT);
      s1b[i] = __hip_atomic_load(p1 + 1, __ATOMIC_RELAXED, __HIP_MEMORY_SCOPE_AGENT);
    }
#pragma unroll
    for (int i = 0; i < 4; ++i) {
      int c = i * 512 + tid;
      *(u64*)(smem + AH_B + (size_t)c * 16)     = s0a[i];
      *(u64*)(smem + AH_B + (size_t)c * 16 + 8) = s0b[i];
    }
    __syncthreads();

    float hp = 0.f;
    for (int half = 0; half < 2; ++half) {
      const int rtoff = half * 16;

      // MFMA waves: wv0 -> ct0 (nh+ni), wv1 -> mode ct
      if (!last && wv < 2) {
        const int cslot = (wv == 0) ? 0 : csel;
        const char* bb = smem + BW_B + cslot * 32768;
        const char* ab = smem + AH_B;
        f32x4 acc0 = {0.f, 0.f, 0.f, 0.f};
        f32x4 acc1 = {0.f, 0.f, 0.f, 0.f};
        f32x4 acc2 = {0.f, 0.f, 0.f, 0.f};
        f32x4 acc3 = {0.f, 0.f, 0.f, 0.f};
#pragma unroll
        for (int ks4 = 0; ks4 < 4; ++ks4) {
#pragma unroll
          for (int q4 = 0; q4 < 4; ++q4) {
            int ks = ks4 * 4 + q4;
            bf16x8 ahh = *(const bf16x8*)(ab + ks * 1024 + lane * 16);
            bf16x8 ahl = *(const bf16x8*)(ab + (16 + ks) * 1024 + lane * 16);
            bf16x8 bhh = *(const bf16x8*)(bb + ks * 1024 + lane * 16);
            bf16x8 bhl = *(const bf16x8*)(bb + (16 + ks) * 1024 + lane * 16);
            f32x4& acc = (q4 == 0) ? acc0 : (q4 == 1) ? acc1 : (q4 == 2) ? acc2 : acc3;
            acc = __builtin_amdgcn_mfma_f32_16x16x32_bf16(ahh, bhh, acc, 0, 0, 0);
            acc = __builtin_amdgcn_mfma_f32_16x16x32_bf16(ahh, bhl, acc, 0, 0, 0);
            acc = __builtin_amdgcn_mfma_f32_16x16x32_bf16(ahl, bhh, acc, 0, 0, 0);
          }
        }
        f32x4 accA = acc0 + acc1;
        f32x4 accB = acc2 + acc3;
        f32x4 acc = accA + accB;
        const int prow = ((wv == 0) ? 16 : 0) + (lane & 15);
        const int pcol = rtoff + ((lane >> 4) << 2);
#pragma unroll
        for (int q = 0; q < 4; ++q) LP[PRE_F + prow * 33 + pcol + q] = acc[q];
      }

      // out-dot: 256 tasks (16 local batches x 16 ks)
      if (tid >= 128 && tid < 384) {
        const int tA = tid - 128;
        const int bl = tA & 15, ks = tA >> 4;
        const int b = rtoff + bl;
        const float* woc = &LP[WOC_F];
        float oa = 0.f;
#pragma unroll
        for (int c = 0; c < 4; ++c) {
          const uint4 wh = *(const uint4*)(smem + AH_B + ks * 1024 + (bl | (c << 4)) * 16);
          const uint4 wl = *(const uint4*)(smem + AH_B + (16 + ks) * 1024 + (bl | (c << 4)) * 16);
          int k0 = ks * 32 + c * 8;
          oa = fmaf(bfhilo(wh.x & 0xFFFFu, wl.x & 0xFFFFu), woc[k0 + 0], oa);
          oa = fmaf(bfhilo(wh.x >> 16, wl.x >> 16), woc[k0 + 1], oa);
          oa = fmaf(bfhilo(wh.y & 0xFFFFu, wl.y & 0xFFFFu), woc[k0 + 2], oa);
          oa = fmaf(bfhilo(wh.y >> 16, wl.y >> 16), woc[k0 + 3], oa);
          oa = fmaf(bfhilo(wh.z & 0xFFFFu, wl.z & 0xFFFFu), woc[k0 + 4], oa);
          oa = fmaf(bfhilo(wh.z >> 16, wl.z >> 16), woc[k0 + 5], oa);
          oa = fmaf(bfhilo(wh.w & 0xFFFFu, wl.w & 0xFFFFu), woc[k0 + 6], oa);
          oa = fmaf(bfhilo(wh.w >> 16, wl.w >> 16), woc[k0 + 7], oa);
        }
        LP[ORED_F + b * 17 + ks] = oa;
      }

      // hp stash for gate threads whose batch is in this half
      if (tid < 256 && (((tid & 31) >> 4) == half)) {
        const int b = tid & 31, jj = tid >> 5;
        const int k = j0 + jj;
        const int ks = k >> 5, e = k & 7;
        const int ln = (b & 15) | (((k >> 3) & 3) << 4);
        unsigned hh = ah16[(ks * 1024 + ln * 16 + e * 2) >> 1];
        unsigned hl = ah16[((16 + ks) * 1024 + ln * 16 + e * 2) >> 1];
        hp = bfhilo(hh, hl);
      }
      __syncthreads();
      if (half == 0) {
#pragma unroll
        for (int i = 0; i < 4; ++i) {
          int c = i * 512 + tid;
          *(u64*)(smem + AH_B + (size_t)c * 16)     = s1a[i];
          *(u64*)(smem + AH_B + (size_t)c * 16 + 8) = s1b[i];
        }
        __syncthreads();
      }
    }

    // -------- phase C: gates -> shfl pack -> sc1 publish; out reduce+write --------
    if (!last && tid < 256) {
      const int b = tid & 31, jj = tid >> 5;
      float pr = LP[PRE_F + jj * 33 + b];
      float pz = LP[PRE_F + (8 + jj) * 33 + b];
      float pnh = LP[PRE_F + (16 + jj) * 33 + b] + LP[SB_F + 48 + jj];
      float pni;
      if (teacher) {
        pr += LP[XPRE_F + jj * 33 + b] + LP[SB_F + jj];
        pz += LP[XPRE_F + (8 + jj) * 33 + b] + LP[SB_F + 8 + jj];
        pni = LP[XPRE_F + (16 + jj) * 33 + b] + LP[SB_F + 56 + jj];
      } else {
        float xl = LP[XLAST_F + b];
        pr += LP[SB_F + 16 + jj] + LP[SB_F + 32 + jj] * xl;
        pz += LP[SB_F + 24 + jj] + LP[SB_F + 40 + jj] * xl;
        pni = LP[PRE_F + (24 + jj) * 33 + b] + LP[SB_F + 64 + jj] + LP[SB_F + 72 + jj] * xl;
      }
      float rg = 1.f / (1.f + expf(-pr));
      float zg = 1.f / (1.f + expf(-pz));
      float ng = tanhf(fmaf(rg, pnh, pni));
      float hv = fmaf(zg, hp - ng, ng);
      float hvp = __shfl_xor(hv, 32, 64);   // partner dim (jj^1), same batch
      if ((jj & 1) == 0) {
        unsigned h0h = rne16(hv), h1h = rne16(hvp);
        float r0 = hv  - __uint_as_float(h0h << 16);
        float r1 = hvp - __uint_as_float(h1h << 16);
        unsigned hw = h0h | (h1h << 16);
        unsigned lw = rne16(r0) | (rne16(r1) << 16);
        unsigned* dhh = (unsigned*)(HHn + (size_t)(bg0 + b) * 512 + j0 + jj);
        unsigned* dhl = (unsigned*)(HLn + (size_t)(bg0 + b) * 512 + j0 + jj);
        __hip_atomic_store(dhh, hw, __ATOMIC_RELAXED, __HIP_MEMORY_SCOPE_AGENT);
        __hip_atomic_store(dhl, lw, __ATOMIC_RELAXED, __HIP_MEMORY_SCOPE_AGENT);
      }
    }
    if (t >= 1 && tid >= 256 && tid < 288) {
      const int b = tid - 256;
      float o = LP[SB_F + 80];
#pragma unroll
      for (int i = 0; i < 16; ++i) o += LP[ORED_F + b * 17 + i];
      out[((size_t)(bg0 + b) * 512 + (t - 1)) * 64 + s] = o;
    }

    // -------- barrier: drain sc1 stores (per wave), arrive, overlap stage_x, spin --------
    if (!last) {
      asm volatile("s_waitcnt vmcnt(0)" ::: "memory");
      __syncthreads();
      if (tid == 0)
        __hip_atomic_fetch_add(myctr, 1u, __ATOMIC_RELAXED, __HIP_MEMORY_SCOPE_AGENT);
      stage_x(t + 1);   // h-independent work hidden under the spin
      if (tid == 0) {
        int cnt = 0;
        while (__hip_atomic_load(myctr, __ATOMIC_RELAXED, __HIP_MEMORY_SCOPE_AGENT) < target) {
          __builtin_amdgcn_s_sleep(2);
          if (++cnt > 16384) break;   // escape hatch: wrong answer instead of hang
        }
      }
      __syncthreads();
      target += 64;
    }
  }
}

extern "C" void kernel_launch(void* const* d_in, const int* in_sizes, int n_in,
                              void* d_out, int out_size, void* d_ws, size_t ws_size,
                              hipStream_t stream) {
  (void)in_sizes; (void)n_in; (void)out_size;
  const float* x    = (const float*)d_in[0];
  const float* tp   = (const float*)d_in[1];
  const int*   mask = (const int*)d_in[2];
  const float* W_ih = (const float*)d_in[3];
  const float* W_hh = (const float*)d_in[4];
  const float* b_ih = (const float*)d_in[5];
  const float* b_hh = (const float*)d_in[6];
  const float* W_out= (const float*)d_in[7];
  const float* b_out= (const float*)d_in[8];
  float* out = (float*)d_out;
  if (ws_size < (size_t)WS_NEEDED) return;
  unsigned short* planes = (unsigned short*)d_ws;
  unsigned* ctr = (unsigned*)((char*)d_ws + CTR_OFF);
  hipMemsetAsync(ctr, 0, 4096, stream);
  hipFuncSetAttribute((const void*)gru_persistent,
                      hipFuncAttributeMaxDynamicSharedMemorySize, LDS_BYTES);
  hipLaunchKernelGGL(gru_persistent, dim3(256), dim3(TB), LDS_BYTES, stream,
                     x, tp, mask, W_ih, W_hh, b_ih, b_hh, W_out, b_out, planes, ctr, out);
}

// Round 5
// 3473.259 us; speedup vs baseline: 9.0499x; 1.5882x over previous
//
#include <hip/hip_runtime.h>
#include <math.h>

// B=128, T=512, D=64, H=512. Grid: 64 dim-slices (8 h-dims each) x 4 batch-groups (32 batches).
// Gates via split-bf16 MFMA (3-term). h exchange:
//   HIST mode (ws >= ~128.3MB): write-once per-step buffers; producers publish via sc1 atomic
//   stores (visible at LLC), consumers use PLAIN CACHED uint4 loads (write-once => no staleness;
//   same-XCD WGs dedup through L2).
//   FALLBACK mode: round-4 proven sc1-atomic 2-buffer ring.
// Barrier = relaxed agent fetch_add + relaxed spin, ordered by per-wave vmcnt(0) drain.
#define TB 512

typedef __attribute__((ext_vector_type(8))) short bf16x8;
typedef __attribute__((ext_vector_type(4))) float f32x4;
typedef unsigned long long u64;

// LDS layout. Byte offsets for frag regions, float offsets for f32 regions.
#define BW_B   0        // 3 ct x 2 term x 16 ks x 1024B = 98304  (weight B-frags)
#define AH_B   98304    // 2 term x 16 ks x 1024B = 32768         (h A-frags, one batch-half)
#define PRE_F  32768    // f32[32][33]  (gate preacts)
#define XPRE_F 33824    // f32[24][33]  (teacher x-dot: r8,z8,n8)
#define ORED_F 34616    // f32[32][17]  (out partials)
#define WOC_F  35160    // f32[512]     (W_out column s)
#define WIH_F  35672    // f32[24][66]  (W_ih slice rows)
#define SB_F   37256    // f32[96]      (biases; [80]=b_out[s])
#define XLAST_F 37352   // f32[32]      (x last channel, AR)
#define MSK_F  37384    // int[512]     (samp mask staged)
#define LDS_FLOATS 37896
#define LDS_BYTES (LDS_FLOATS * 4)   // 151584

#define STEP_BYTES 262144            // per-step h buffer: 4 groups x 64KB
#define GRP_BYTES  65536
#define HIST_NEEDED (4096ull + 513ull * STEP_BYTES)
#define PLANE_STRIDE 262144          // fallback ring: bytes per (HH,HL) plane pair
#define FB_NEEDED (4096ull + 2ull * PLANE_STRIDE)

__device__ __forceinline__ unsigned rne16(float f) {
  unsigned u = __float_as_uint(f);
  return (u + 0x7FFFu + ((u >> 16) & 1u)) >> 16;
}
__device__ __forceinline__ float bfhilo(unsigned hh, unsigned hl) {
  return __uint_as_float(hh << 16) + __uint_as_float(hl << 16);
}

__global__ __launch_bounds__(TB) void gru_persistent(
    const float* __restrict__ x, const float* __restrict__ tp, const int* __restrict__ mask,
    const float* __restrict__ W_ih, const float* __restrict__ W_hh,
    const float* __restrict__ b_ih, const float* __restrict__ b_hh,
    const float* __restrict__ W_out, const float* __restrict__ b_out,
    char* __restrict__ data, unsigned* __restrict__ ctr,
    float* __restrict__ out, int hmode)
{
  extern __shared__ char smem[];
  float* LP = (float*)smem;
  int* MSK = (int*)&LP[MSK_F];
  const int tid = threadIdx.x;
  const int wg  = blockIdx.x;
  const int s   = wg & 63;
  const int g   = wg >> 6;
  const int bg0 = g * 32;
  const int j0  = 8 * s;
  const int lane = tid & 63;
  const int wv   = tid >> 6;

  unsigned short* planes = (unsigned short*)data;   // fallback ring

  // ---------------- init ----------------
  MSK[tid] = mask[tid];
  if (tid < 65) {
    for (int p = 0; p < 24; ++p) {
      int row = (p < 8) ? (j0 + p) : (p < 16) ? (512 + j0 + (p - 8)) : (1024 + j0 + (p - 16));
      LP[WIH_F + p * 66 + tid] = W_ih[(size_t)row * 65 + tid];
    }
  }
  LP[WOC_F + tid] = W_out[(size_t)tid * 64 + s];
  if (tid < 16) {
    int row = (tid < 8) ? (j0 + tid) : (512 + j0 + (tid - 8));
    const float* wi = W_ih + (size_t)row * 65;
    float bt = b_ih[row] + b_hh[row];
    float bp = 0.f;
    for (int d = 0; d < 64; ++d) bp = fmaf(wi[d], b_out[d], bp);
    LP[SB_F + tid]      = bt;        // teacher rz bias
    LP[SB_F + 16 + tid] = bt + bp;   // AR rz bias
    LP[SB_F + 32 + tid] = wi[64];    // xlast coef rz
  } else if (tid < 24) {
    int jj = tid - 16;
    int row = 1024 + j0 + jj;
    const float* wi = W_ih + (size_t)row * 65;
    float bp = 0.f;
    for (int d = 0; d < 64; ++d) bp = fmaf(wi[d], b_out[d], bp);
    LP[SB_F + 48 + jj] = b_hh[row];
    LP[SB_F + 56 + jj] = b_ih[row];
    LP[SB_F + 64 + jj] = b_ih[row] + bp;
    LP[SB_F + 72 + jj] = wi[64];
  }
  if (tid == 0) LP[SB_F + 80] = b_out[s];

  // zero h0 with sc1 stores (visible at coherence point)
  if (tid < 32) {
    if (hmode) {
      const int half = tid >> 4, ln = (tid & 15) | ((s & 3) << 4), ks = s >> 2;
      char* dst = data + (size_t)g * GRP_BYTES;
      u64* c0 = (u64*)(dst + (size_t)(((0 * 16 + ks) * 2 + half) * 64 + ln) * 16);
      u64* c1 = (u64*)(dst + (size_t)(((1 * 16 + ks) * 2 + half) * 64 + ln) * 16);
      __hip_atomic_store(c0,     0ull, __ATOMIC_RELAXED, __HIP_MEMORY_SCOPE_AGENT);
      __hip_atomic_store(c0 + 1, 0ull, __ATOMIC_RELAXED, __HIP_MEMORY_SCOPE_AGENT);
      __hip_atomic_store(c1,     0ull, __ATOMIC_RELAXED, __HIP_MEMORY_SCOPE_AGENT);
      __hip_atomic_store(c1 + 1, 0ull, __ATOMIC_RELAXED, __HIP_MEMORY_SCOPE_AGENT);
    } else {
      u64* hh0 = (u64*)(planes + (size_t)(bg0 + tid) * 512 + j0);
      u64* hl0 = (u64*)(planes + 65536 + (size_t)(bg0 + tid) * 512 + j0);
      __hip_atomic_store(hh0,     0ull, __ATOMIC_RELAXED, __HIP_MEMORY_SCOPE_AGENT);
      __hip_atomic_store(hh0 + 1, 0ull, __ATOMIC_RELAXED, __HIP_MEMORY_SCOPE_AGENT);
      __hip_atomic_store(hl0,     0ull, __ATOMIC_RELAXED, __HIP_MEMORY_SCOPE_AGENT);
      __hip_atomic_store(hl0 + 1, 0ull, __ATOMIC_RELAXED, __HIP_MEMORY_SCOPE_AGENT);
    }
  }
  __syncthreads();

  // build weight B-frags (split bf16). thread = k.
  {
    const int k = tid;
    const float* wo = W_out + (size_t)k * 64;
    unsigned short* bw16 = (unsigned short*)(smem + BW_B);
    for (int rr = 0; rr < 48; ++rr) {
      int c, col; float w;
      if (rr < 16) {
        c = 1; col = rr;
        int row = (rr < 8) ? (j0 + rr) : (512 + j0 + rr - 8);
        w = W_hh[(size_t)row * 512 + k];
      } else if (rr < 24) {
        c = 0; col = rr - 16;
        w = W_hh[(size_t)(1024 + j0 + rr - 16) * 512 + k];
      } else {
        int p, whrow;
        if (rr < 32) { c = 0; col = rr - 24 + 8; p = 16 + (rr - 24); whrow = -1; }
        else if (rr < 40) { c = 2; col = rr - 32; p = rr - 32; whrow = j0 + rr - 32; }
        else { c = 2; col = rr - 40 + 8; p = 8 + (rr - 40); whrow = 512 + j0 + rr - 40; }
        const float* wr = &LP[WIH_F + p * 66];
        float a = 0.f;
#pragma unroll 8
        for (int d = 0; d < 64; ++d) a = fmaf(wr[d], wo[d], a);
        w = a + (whrow >= 0 ? W_hh[(size_t)whrow * 512 + k] : 0.f);
      }
      unsigned wh = rne16(w);
      float resid = w - __uint_as_float(wh << 16);
      unsigned wl = rne16(resid);
      int base = c * 32768 + (k >> 5) * 1024 + (col | (((k >> 3) & 3) << 4)) * 16 + (k & 7) * 2;
      bw16[base >> 1] = (unsigned short)wh;
      bw16[(base + 16384) >> 1] = (unsigned short)wl;
    }
  }
  __syncthreads();

  // teacher x-dot staging for step tt (h-independent; runs in spin windows)
  auto stage_x = [&](int tt) {
    if (tt >= 512) return;
    if (MSK[tt] != 0) {
      for (int task = tid; task < 768; task += TB) {
        const int xr = task >> 5, b = task & 31;
        const float* wrow = &LP[WIH_F + xr * 66];
        size_t ti = (size_t)(bg0 + b) * 512 + tt;
        float del = tp[ti] - (tt > 0 ? tp[ti - 1] : 0.f);
        float xa = wrow[64] * del;
        const float4* x4 = (const float4*)(x + ti * 64);
#pragma unroll
        for (int d4 = 0; d4 < 16; ++d4) {
          float4 xv = x4[d4];
          xa = fmaf(wrow[d4 * 4 + 0], xv.x, xa);
          xa = fmaf(wrow[d4 * 4 + 1], xv.y, xa);
          xa = fmaf(wrow[d4 * 4 + 2], xv.z, xa);
          xa = fmaf(wrow[d4 * 4 + 3], xv.w, xa);
        }
        LP[XPRE_F + xr * 33 + b] = xa;
      }
    } else if (tid < 32) {
      LP[XLAST_F + tid] = x[((size_t)(bg0 + tid) * 512 + tt) * 64 + 63];
    }
  };

  stage_x(0);

  unsigned target = 64;
  unsigned* myctr = &ctr[g * 64];

  // initial barrier: h0 zeros + stage_x(0) done
  asm volatile("s_waitcnt vmcnt(0)" ::: "memory");
  __syncthreads();
  if (tid == 0) {
    __hip_atomic_fetch_add(myctr, 1u, __ATOMIC_RELAXED, __HIP_MEMORY_SCOPE_AGENT);
    int cnt = 0;
    while (__hip_atomic_load(myctr, __ATOMIC_RELAXED, __HIP_MEMORY_SCOPE_AGENT) < target) {
      __builtin_amdgcn_s_sleep(2);
      if (++cnt > 16384) break;
    }
  }
  __syncthreads();
  target += 64;

  const unsigned short* ah16 = (const unsigned short*)(smem + AH_B);

  for (int t = 0; t <= 512; ++t) {
    const bool last = (t == 512);
    const bool teacher = (!last) && (MSK[t] != 0);
    const int csel = teacher ? 1 : 2;

    // -------- phase A: fetch both batch-halves of h; write half0 frags --------
    uint4 h0v[4], h1v[4];
    if (hmode) {
      const char* src = data + (size_t)t * STEP_BYTES + (size_t)g * GRP_BYTES;
#pragma unroll
      for (int i = 0; i < 4; ++i) {
        int c = i * 512 + tid;          // AH chunk id 0..2047
        int sg = c >> 6, ln = c & 63;
        h0v[i] = *(const uint4*)(src + (size_t)((sg * 2 + 0) * 64 + ln) * 16);
        h1v[i] = *(const uint4*)(src + (size_t)((sg * 2 + 1) * 64 + ln) * 16);
      }
    } else {
      const int cur = t & 1;
      const unsigned short* HHc = planes + (size_t)cur * (PLANE_STRIDE / 2);
      const unsigned short* HLc = HHc + 65536;
#pragma unroll
      for (int i = 0; i < 4; ++i) {
        int c = i * 512 + tid;
        int sg = c >> 6, ln = c & 63;
        int term = sg >> 4, ks = sg & 15;
        const unsigned short* pl = term ? HLc : HHc;
        const unsigned short* src0 = pl + ((size_t)(bg0 + (ln & 15)) * 512 + ks * 32 + ((ln >> 4) & 3) * 8);
        const u64* p0 = (const u64*)src0;
        const u64* p1 = (const u64*)(src0 + 16 * 512);
        u64 a0 = __hip_atomic_load(p0,     __ATOMIC_RELAXED, __HIP_MEMORY_SCOPE_AGENT);
        u64 a1 = __hip_atomic_load(p0 + 1, __ATOMIC_RELAXED, __HIP_MEMORY_SCOPE_AGENT);
        u64 b0 = __hip_atomic_load(p1,     __ATOMIC_RELAXED, __HIP_MEMORY_SCOPE_AGENT);
        u64 b1 = __hip_atomic_load(p1 + 1, __ATOMIC_RELAXED, __HIP_MEMORY_SCOPE_AGENT);
        h0v[i] = uint4{(unsigned)a0, (unsigned)(a0 >> 32), (unsigned)a1, (unsigned)(a1 >> 32)};
        h1v[i] = uint4{(unsigned)b0, (unsigned)(b0 >> 32), (unsigned)b1, (unsigned)(b1 >> 32)};
      }
    }
#pragma unroll
    for (int i = 0; i < 4; ++i) {
      int c = i * 512 + tid;
      *(uint4*)(smem + AH_B + (size_t)c * 16) = h0v[i];
    }
    __syncthreads();

    float hp = 0.f;
    for (int half = 0; half < 2; ++half) {
      const int rtoff = half * 16;

      // MFMA waves: wv0 -> ct0 (nh+ni), wv1 -> mode ct
      if (!last && wv < 2) {
        const int cslot = (wv == 0) ? 0 : csel;
        const char* bb = smem + BW_B + cslot * 32768;
        const char* ab = smem + AH_B;
        f32x4 acc0 = {0.f, 0.f, 0.f, 0.f};
        f32x4 acc1 = {0.f, 0.f, 0.f, 0.f};
        f32x4 acc2 = {0.f, 0.f, 0.f, 0.f};
        f32x4 acc3 = {0.f, 0.f, 0.f, 0.f};
#pragma unroll
        for (int ks4 = 0; ks4 < 4; ++ks4) {
#pragma unroll
          for (int q4 = 0; q4 < 4; ++q4) {
            int ks = ks4 * 4 + q4;
            bf16x8 ahh = *(const bf16x8*)(ab + ks * 1024 + lane * 16);
            bf16x8 ahl = *(const bf16x8*)(ab + (16 + ks) * 1024 + lane * 16);
            bf16x8 bhh = *(const bf16x8*)(bb + ks * 1024 + lane * 16);
            bf16x8 bhl = *(const bf16x8*)(bb + (16 + ks) * 1024 + lane * 16);
            f32x4& acc = (q4 == 0) ? acc0 : (q4 == 1) ? acc1 : (q4 == 2) ? acc2 : acc3;
            acc = __builtin_amdgcn_mfma_f32_16x16x32_bf16(ahh, bhh, acc, 0, 0, 0);
            acc = __builtin_amdgcn_mfma_f32_16x16x32_bf16(ahh, bhl, acc, 0, 0, 0);
            acc = __builtin_amdgcn_mfma_f32_16x16x32_bf16(ahl, bhh, acc, 0, 0, 0);
          }
        }
        f32x4 accA = acc0 + acc1;
        f32x4 accB = acc2 + acc3;
        f32x4 acc = accA + accB;
        const int prow = ((wv == 0) ? 16 : 0) + (lane & 15);
        const int pcol = rtoff + ((lane >> 4) << 2);
#pragma unroll
        for (int q = 0; q < 4; ++q) LP[PRE_F + prow * 33 + pcol + q] = acc[q];
      }

      // out-dot: 256 tasks (16 local batches x 16 ks)
      if (tid >= 128 && tid < 384) {
        const int tA = tid - 128;
        const int bl = tA & 15, ks = tA >> 4;
        const int b = rtoff + bl;
        const float* woc = &LP[WOC_F];
        float oa = 0.f;
#pragma unroll
        for (int c = 0; c < 4; ++c) {
          const uint4 wh = *(const uint4*)(smem + AH_B + ks * 1024 + (bl | (c << 4)) * 16);
          const uint4 wl = *(const uint4*)(smem + AH_B + (16 + ks) * 1024 + (bl | (c << 4)) * 16);
          int k0 = ks * 32 + c * 8;
          oa = fmaf(bfhilo(wh.x & 0xFFFFu, wl.x & 0xFFFFu), woc[k0 + 0], oa);
          oa = fmaf(bfhilo(wh.x >> 16, wl.x >> 16), woc[k0 + 1], oa);
          oa = fmaf(bfhilo(wh.y & 0xFFFFu, wl.y & 0xFFFFu), woc[k0 + 2], oa);
          oa = fmaf(bfhilo(wh.y >> 16, wl.y >> 16), woc[k0 + 3], oa);
          oa = fmaf(bfhilo(wh.z & 0xFFFFu, wl.z & 0xFFFFu), woc[k0 + 4], oa);
          oa = fmaf(bfhilo(wh.z >> 16, wl.z >> 16), woc[k0 + 5], oa);
          oa = fmaf(bfhilo(wh.w & 0xFFFFu, wl.w & 0xFFFFu), woc[k0 + 6], oa);
          oa = fmaf(bfhilo(wh.w >> 16, wl.w >> 16), woc[k0 + 7], oa);
        }
        LP[ORED_F + b * 17 + ks] = oa;
      }

      // hp stash for gate threads whose batch is in this half
      if (tid < 256 && (((tid & 31) >> 4) == half)) {
        const int b = tid & 31, jj = tid >> 5;
        const int k = j0 + jj;
        const int ks = k >> 5, e = k & 7;
        const int ln = (b & 15) | (((k >> 3) & 3) << 4);
        unsigned hh = ah16[(ks * 1024 + ln * 16 + e * 2) >> 1];
        unsigned hl = ah16[((16 + ks) * 1024 + ln * 16 + e * 2) >> 1];
        hp = bfhilo(hh, hl);
      }
      __syncthreads();
      if (half == 0) {
#pragma unroll
        for (int i = 0; i < 4; ++i) {
          int c = i * 512 + tid;
          *(uint4*)(smem + AH_B + (size_t)c * 16) = h1v[i];
        }
        __syncthreads();
      }
    }

    // -------- gates -> shfl pack -> sc1 publish --------
    if (!last && tid < 256) {
      const int b = tid & 31, jj = tid >> 5;
      float pr = LP[PRE_F + jj * 33 + b];
      float pz = LP[PRE_F + (8 + jj) * 33 + b];
      float pnh = LP[PRE_F + (16 + jj) * 33 + b] + LP[SB_F + 48 + jj];
      float pni;
      if (teacher) {
        pr += LP[XPRE_F + jj * 33 + b] + LP[SB_F + jj];
        pz += LP[XPRE_F + (8 + jj) * 33 + b] + LP[SB_F + 8 + jj];
        pni = LP[XPRE_F + (16 + jj) * 33 + b] + LP[SB_F + 56 + jj];
      } else {
        float xl = LP[XLAST_F + b];
        pr += LP[SB_F + 16 + jj] + LP[SB_F + 32 + jj] * xl;
        pz += LP[SB_F + 24 + jj] + LP[SB_F + 40 + jj] * xl;
        pni = LP[PRE_F + (24 + jj) * 33 + b] + LP[SB_F + 64 + jj] + LP[SB_F + 72 + jj] * xl;
      }
      float rg = 1.f / (1.f + expf(-pr));
      float zg = 1.f / (1.f + expf(-pz));
      float ng = tanhf(fmaf(rg, pnh, pni));
      float hv = fmaf(zg, hp - ng, ng);
      float hvp = __shfl_xor(hv, 32, 64);   // partner dim (jj^1), same batch
      if ((jj & 1) == 0) {
        unsigned h0h = rne16(hv), h1h = rne16(hvp);
        float r0 = hv  - __uint_as_float(h0h << 16);
        float r1 = hvp - __uint_as_float(h1h << 16);
        unsigned hw = h0h | (h1h << 16);
        unsigned lw = rne16(r0) | (rne16(r1) << 16);
        unsigned *dhh, *dhl;
        if (hmode) {
          char* dst = data + (size_t)(t + 1) * STEP_BYTES + (size_t)g * GRP_BYTES;
          const int half = b >> 4, ln = (b & 15) | ((s & 3) << 4), ks = s >> 2;
          dhh = (unsigned*)(dst + (size_t)(((0 * 16 + ks) * 2 + half) * 64 + ln) * 16 + jj * 2);
          dhl = (unsigned*)(dst + (size_t)(((1 * 16 + ks) * 2 + half) * 64 + ln) * 16 + jj * 2);
        } else {
          const int cur = t & 1;
          unsigned short* HHn = (unsigned short*)(planes + (size_t)(cur ^ 1) * (PLANE_STRIDE / 2));
          unsigned short* HLn = HHn + 65536;
          dhh = (unsigned*)(HHn + (size_t)(bg0 + b) * 512 + j0 + jj);
          dhl = (unsigned*)(HLn + (size_t)(bg0 + b) * 512 + j0 + jj);
        }
        __hip_atomic_store(dhh, hw, __ATOMIC_RELAXED, __HIP_MEMORY_SCOPE_AGENT);
        __hip_atomic_store(dhl, lw, __ATOMIC_RELAXED, __HIP_MEMORY_SCOPE_AGENT);
      }
    }

    // -------- barrier: drain (per wave), arrive, hide out-write + stage_x, spin --------
    if (!last) {
      asm volatile("s_waitcnt vmcnt(0)" ::: "memory");
      __syncthreads();
      if (tid == 0)
        __hip_atomic_fetch_add(myctr, 1u, __ATOMIC_RELAXED, __HIP_MEMORY_SCOPE_AGENT);
      if (t >= 1 && tid >= 256 && tid < 288) {
        const int b = tid - 256;
        float o = LP[SB_F + 80];
#pragma unroll
        for (int i = 0; i < 16; ++i) o += LP[ORED_F + b * 17 + i];
        out[((size_t)(bg0 + b) * 512 + (t - 1)) * 64 + s] = o;
      }
      stage_x(t + 1);   // h-independent work hidden under the spin
      if (tid == 0) {
        int cnt = 0;
        while (__hip_atomic_load(myctr, __ATOMIC_RELAXED, __HIP_MEMORY_SCOPE_AGENT) < target) {
          __builtin_amdgcn_s_sleep(2);
          if (++cnt > 16384) break;   // escape hatch: wrong answer instead of hang
        }
      }
      __syncthreads();
      target += 64;
    } else {
      // t == 512: ORED holds h_arr[511] partials; write the final out row
      if (tid >= 256 && tid < 288) {
        const int b = tid - 256;
        float o = LP[SB_F + 80];
#pragma unroll
        for (int i = 0; i < 16; ++i) o += LP[ORED_F + b * 17 + i];
        out[((size_t)(bg0 + b) * 512 + 511) * 64 + s] = o;
      }
    }
  }
}

extern "C" void kernel_launch(void* const* d_in, const int* in_sizes, int n_in,
                              void* d_out, int out_size, void* d_ws, size_t ws_size,
                              hipStream_t stream) {
  (void)in_sizes; (void)n_in; (void)out_size;
  const float* x    = (const float*)d_in[0];
  const float* tp   = (const float*)d_in[1];
  const int*   mask = (const int*)d_in[2];
  const float* W_ih = (const float*)d_in[3];
  const float* W_hh = (const float*)d_in[4];
  const float* b_ih = (const float*)d_in[5];
  const float* b_hh = (const float*)d_in[6];
  const float* W_out= (const float*)d_in[7];
  const float* b_out= (const float*)d_in[8];
  float* out = (float*)d_out;
  if (ws_size < FB_NEEDED) return;
  int hmode = (ws_size >= HIST_NEEDED) ? 1 : 0;
  unsigned* ctr = (unsigned*)d_ws;
  char* dataptr = (char*)d_ws + 4096;
  hipMemsetAsync(ctr, 0, 4096, stream);
  hipFuncSetAttribute((const void*)gru_persistent,
                      hipFuncAttributeMaxDynamicSharedMemorySize, LDS_BYTES);
  hipLaunchKernelGGL(gru_persistent, dim3(256), dim3(TB), LDS_BYTES, stream,
                     x, tp, mask, W_ih, W_hh, b_ih, b_hh, W_out, b_out, dataptr, ctr, out, hmode);
}

// Round 6
// 3395.758 us; speedup vs baseline: 9.2564x; 1.0228x over previous
//
#include <hip/hip_runtime.h>
#include <math.h>

// B=128, T=512, D=64, H=512. Grid: 64 dim-slices (8 h-dims each) x 4 batch-groups (32 batches).
// Gates via split-bf16 MFMA (3-term), B-fragments in REGISTERS (6 MFMA waves: 3 ct x 2 K-half).
// h exchange: write-once per-step hist buffers; producers publish via sc1 stores, consumers
// plain cached uint4 loads (write-once => fresh; same-XCD WGs dedup via L2). Fallback (small ws):
// 2-buffer ring with sc1 atomic loads.
// Barrier: per-WG flag words (parallel sc1 stores) + wave0 64-lane flag load + ballot detect.
#define TB 512

typedef __attribute__((ext_vector_type(8))) short bf16x8;
typedef __attribute__((ext_vector_type(4))) float f32x4;
typedef unsigned long long u64;

// LDS: AH2 (both halves of h frags) bytes [0,65536); init-time BW frags [0,98304); floats after.
#define FBASE  24576               // float index of byte 98304
#define PREP_F (FBASE)             // 2 x 32 x 33 f32 (K-half partial preacts)
#define XPRE_F (FBASE + 2112)      // 24 x 33 (teacher x-dot r8,z8,n8)
#define ORED_F (FBASE + 2904)      // 32 x 17 (out partials)
#define WOC_F  (FBASE + 3448)      // 512    (W_out column s)
#define WIH_F  (FBASE + 3960)      // 24 x 66
#define SB_F   (FBASE + 5544)      // 96 biases ([80]=b_out[s])
#define XLAST_F (FBASE + 5640)     // 32
#define MSK_F  (FBASE + 5672)      // 512 ints
#define LDS_FLOATS (FBASE + 6184)
#define LDS_BYTES (LDS_FLOATS * 4) // 123040

#define STEP_BYTES 262144          // per-step h buffer: 4 groups x 64KB
#define GRP_BYTES  65536
#define HIST_NEEDED (4096ull + 513ull * STEP_BYTES)
#define FB_NEEDED   (4096ull + 2ull * STEP_BYTES)

__device__ __forceinline__ unsigned rne16(float f) {
  unsigned u = __float_as_uint(f);
  return (u + 0x7FFFu + ((u >> 16) & 1u)) >> 16;
}
__device__ __forceinline__ float bfhilo(unsigned hh, unsigned hl) {
  return __uint_as_float(hh << 16) + __uint_as_float(hl << 16);
}

__global__ __launch_bounds__(TB, 2) void gru_persistent(
    const float* __restrict__ x, const float* __restrict__ tp, const int* __restrict__ mask,
    const float* __restrict__ W_ih, const float* __restrict__ W_hh,
    const float* __restrict__ b_ih, const float* __restrict__ b_hh,
    const float* __restrict__ W_out, const float* __restrict__ b_out,
    char* __restrict__ data, unsigned* __restrict__ flags,
    float* __restrict__ out, int hmode)
{
  extern __shared__ char smem[];
  float* LP = (float*)smem;
  int* MSK = (int*)&LP[MSK_F];
  const int tid = threadIdx.x;
  const int wg  = blockIdx.x;
  const int s   = wg & 63;
  const int g   = wg >> 6;
  const int bg0 = g * 32;
  const int j0  = 8 * s;
  const int lane = tid & 63;
  const int wv   = tid >> 6;
  const int myct = wv >> 1, mykh = wv & 1;   // MFMA wave role (wv<6)

  // ---------------- init ----------------
  MSK[tid] = mask[tid];
  if (tid < 65) {
    for (int p = 0; p < 24; ++p) {
      int row = (p < 8) ? (j0 + p) : (p < 16) ? (512 + j0 + (p - 8)) : (1024 + j0 + (p - 16));
      LP[WIH_F + p * 66 + tid] = W_ih[(size_t)row * 65 + tid];
    }
  }
  LP[WOC_F + tid] = W_out[(size_t)tid * 64 + s];
  if (tid < 16) {
    int row = (tid < 8) ? (j0 + tid) : (512 + j0 + (tid - 8));
    const float* wi = W_ih + (size_t)row * 65;
    float bt = b_ih[row] + b_hh[row];
    float bp = 0.f;
    for (int d = 0; d < 64; ++d) bp = fmaf(wi[d], b_out[d], bp);
    LP[SB_F + tid]      = bt;        // teacher rz bias
    LP[SB_F + 16 + tid] = bt + bp;   // AR rz bias
    LP[SB_F + 32 + tid] = wi[64];    // xlast coef rz
  } else if (tid < 24) {
    int jj = tid - 16;
    int row = 1024 + j0 + jj;
    const float* wi = W_ih + (size_t)row * 65;
    float bp = 0.f;
    for (int d = 0; d < 64; ++d) bp = fmaf(wi[d], b_out[d], bp);
    LP[SB_F + 48 + jj] = b_hh[row];
    LP[SB_F + 56 + jj] = b_ih[row];
    LP[SB_F + 64 + jj] = b_ih[row] + bp;
    LP[SB_F + 72 + jj] = wi[64];
  }
  if (tid == 0) LP[SB_F + 80] = b_out[s];
  // zero h0 buffer (parity/step 0): WG zeros its 1KB share of the group slab
  if (tid < 64) {
    u64* p = (u64*)(data + (size_t)g * GRP_BYTES + (size_t)s * 1024 + tid * 16);
    __hip_atomic_store(p,     0ull, __ATOMIC_RELAXED, __HIP_MEMORY_SCOPE_AGENT);
    __hip_atomic_store(p + 1, 0ull, __ATOMIC_RELAXED, __HIP_MEMORY_SCOPE_AGENT);
  }
  __syncthreads();

  // build weight B-frags (split bf16) in LDS bytes [0,98304). thread = k.
  {
    const int k = tid;
    const float* wo = W_out + (size_t)k * 64;
    unsigned short* bw16 = (unsigned short*)smem;
    for (int rr = 0; rr < 48; ++rr) {
      int c, col; float w;
      if (rr < 16) {
        c = 1; col = rr;
        int row = (rr < 8) ? (j0 + rr) : (512 + j0 + rr - 8);
        w = W_hh[(size_t)row * 512 + k];
      } else if (rr < 24) {
        c = 0; col = rr - 16;
        w = W_hh[(size_t)(1024 + j0 + rr - 16) * 512 + k];
      } else {
        int p, whrow;
        if (rr < 32) { c = 0; col = rr - 24 + 8; p = 16 + (rr - 24); whrow = -1; }
        else if (rr < 40) { c = 2; col = rr - 32; p = rr - 32; whrow = j0 + rr - 32; }
        else { c = 2; col = rr - 40 + 8; p = 8 + (rr - 40); whrow = 512 + j0 + rr - 40; }
        const float* wr = &LP[WIH_F + p * 66];
        float a = 0.f;
#pragma unroll 8
        for (int d = 0; d < 64; ++d) a = fmaf(wr[d], wo[d], a);
        w = a + (whrow >= 0 ? W_hh[(size_t)whrow * 512 + k] : 0.f);
      }
      unsigned wh = rne16(w);
      float resid = w - __uint_as_float(wh << 16);
      unsigned wl = rne16(resid);
      int base = c * 32768 + (k >> 5) * 1024 + (col | (((k >> 3) & 3) << 4)) * 16 + (k & 7) * 2;
      bw16[base >> 1] = (unsigned short)wh;
      bw16[(base + 16384) >> 1] = (unsigned short)wl;
    }
  }
  __syncthreads();

  // hoist this wave's B-fragments into registers (wv<6): 8 ks x (hi,lo)
  bf16x8 Bh[8], Bl[8];
  if (wv < 6) {
#pragma unroll
    for (int i = 0; i < 8; ++i) {
      Bh[i] = *(const bf16x8*)(smem + myct * 32768 + (mykh * 8 + i) * 1024 + lane * 16);
      Bl[i] = *(const bf16x8*)(smem + myct * 32768 + 16384 + (mykh * 8 + i) * 1024 + lane * 16);
    }
  }

  // teacher x-dot staging for step tt (h-independent; runs in hidden windows)
  auto stage_x = [&](int tt) {
    if (tt >= 512) return;
    if (MSK[tt] != 0) {
      for (int task = tid; task < 768; task += TB) {
        const int xr = task >> 5, b = task & 31;
        const float* wrow = &LP[WIH_F + xr * 66];
        size_t ti = (size_t)(bg0 + b) * 512 + tt;
        float del = tp[ti] - (tt > 0 ? tp[ti - 1] : 0.f);
        float xa = wrow[64] * del;
        const float4* x4 = (const float4*)(x + ti * 64);
#pragma unroll
        for (int d4 = 0; d4 < 16; ++d4) {
          float4 xv = x4[d4];
          xa = fmaf(wrow[d4 * 4 + 0], xv.x, xa);
          xa = fmaf(wrow[d4 * 4 + 1], xv.y, xa);
          xa = fmaf(wrow[d4 * 4 + 2], xv.z, xa);
          xa = fmaf(wrow[d4 * 4 + 3], xv.w, xa);
        }
        LP[XPRE_F + xr * 33 + b] = xa;
      }
    } else if (tid < 32) {
      LP[XLAST_F + tid] = x[((size_t)(bg0 + tid) * 512 + tt) * 64 + 63];
    }
  };

  stage_x(0);

  unsigned* myflags = &flags[g * 64];

  // initial barrier: h0 zeros + B-regs + stage_x(0) done
  asm volatile("s_waitcnt vmcnt(0)" ::: "memory");
  __syncthreads();
  if (tid == 0)
    __hip_atomic_store(&myflags[s], 1u, __ATOMIC_RELAXED, __HIP_MEMORY_SCOPE_AGENT);
  if (wv == 0) {
    int cnt = 0;
    while (true) {
      unsigned v = __hip_atomic_load(&myflags[lane], __ATOMIC_RELAXED, __HIP_MEMORY_SCOPE_AGENT);
      if (__ballot(v < 1u) == 0ull) break;
      __builtin_amdgcn_s_sleep(1);
      if (++cnt > 500000) break;   // escape hatch
    }
  }
  __syncthreads();

  const unsigned short* ah16 = (const unsigned short*)smem;

  for (int t = 0; t <= 512; ++t) {
    const bool last = (t == 512);
    const bool teacher = (!last) && (MSK[t] != 0);
    const int csel = teacher ? 1 : 2;

    // -------- phase A: fetch both batch-halves of h into LDS (single shot) --------
    const char* src = data + (size_t)(hmode ? t : (t & 1)) * STEP_BYTES + (size_t)g * GRP_BYTES;
    uint4 v0[4], v1[4];
    if (hmode) {
#pragma unroll
      for (int i = 0; i < 4; ++i) {
        int c = i * 512 + tid, sg = c >> 6, ln = c & 63;
        v0[i] = *(const uint4*)(src + (size_t)((sg * 2 + 0) * 64 + ln) * 16);
        v1[i] = *(const uint4*)(src + (size_t)((sg * 2 + 1) * 64 + ln) * 16);
      }
    } else {
#pragma unroll
      for (int i = 0; i < 4; ++i) {
        int c = i * 512 + tid, sg = c >> 6, ln = c & 63;
        const u64* p0 = (const u64*)(src + (size_t)((sg * 2 + 0) * 64 + ln) * 16);
        const u64* p1 = (const u64*)(src + (size_t)((sg * 2 + 1) * 64 + ln) * 16);
        u64 a0 = __hip_atomic_load(p0,     __ATOMIC_RELAXED, __HIP_MEMORY_SCOPE_AGENT);
        u64 a1 = __hip_atomic_load(p0 + 1, __ATOMIC_RELAXED, __HIP_MEMORY_SCOPE_AGENT);
        u64 b0 = __hip_atomic_load(p1,     __ATOMIC_RELAXED, __HIP_MEMORY_SCOPE_AGENT);
        u64 b1 = __hip_atomic_load(p1 + 1, __ATOMIC_RELAXED, __HIP_MEMORY_SCOPE_AGENT);
        v0[i] = uint4{(unsigned)a0, (unsigned)(a0 >> 32), (unsigned)a1, (unsigned)(a1 >> 32)};
        v1[i] = uint4{(unsigned)b0, (unsigned)(b0 >> 32), (unsigned)b1, (unsigned)(b1 >> 32)};
      }
    }
#pragma unroll
    for (int i = 0; i < 4; ++i) {
      int c = i * 512 + tid, sg = c >> 6, ln = c & 63;
      *(uint4*)(smem + (size_t)(sg * 1024) + ln * 16)        = v0[i];   // half0
      *(uint4*)(smem + (size_t)((32 + sg) * 1024) + ln * 16) = v1[i];   // half1
    }
    __syncthreads();   // sync A

    // hp stash (gate threads): previous h for own (b, dim)
    float hp = 0.f;
    if (tid < 256) {
      const int b = tid & 31, jj = tid >> 5;
      const int ks = s >> 2, half = b >> 4;
      const int ln = (b & 15) | ((s & 3) << 4);
      unsigned hh = ah16[((half * 32 + ks) * 1024 + ln * 16 + jj * 2) >> 1];
      unsigned hl = ah16[((half * 32 + 16 + ks) * 1024 + ln * 16 + jj * 2) >> 1];
      hp = bfhilo(hh, hl);
    }

    // MFMA waves (wv<6): ct0 always; ct1 on teacher; ct2 on AR. K-half = mykh.
    if (!last && wv < 6 && (myct == 0 || myct == csel)) {
#pragma unroll
      for (int half = 0; half < 2; ++half) {
        f32x4 acc0 = {0.f, 0.f, 0.f, 0.f};
        f32x4 acc1 = {0.f, 0.f, 0.f, 0.f};
        f32x4 acc2 = {0.f, 0.f, 0.f, 0.f};
        f32x4 acc3 = {0.f, 0.f, 0.f, 0.f};
#pragma unroll
        for (int i = 0; i < 8; ++i) {
          const char* abh = smem + (size_t)((half * 32 + mykh * 8 + i) * 1024) + lane * 16;
          bf16x8 ahh = *(const bf16x8*)abh;
          bf16x8 ahl = *(const bf16x8*)(abh + 16 * 1024);
          f32x4& acc = ((i & 3) == 0) ? acc0 : ((i & 3) == 1) ? acc1 : ((i & 3) == 2) ? acc2 : acc3;
          acc = __builtin_amdgcn_mfma_f32_16x16x32_bf16(ahh, Bh[i], acc, 0, 0, 0);
          acc = __builtin_amdgcn_mfma_f32_16x16x32_bf16(ahh, Bl[i], acc, 0, 0, 0);
          acc = __builtin_amdgcn_mfma_f32_16x16x32_bf16(ahl, Bh[i], acc, 0, 0, 0);
        }
        f32x4 acc = (acc0 + acc1) + (acc2 + acc3);
        const int prow = (myct == 0 ? 16 : 0) + (lane & 15);
        const int pcol = half * 16 + ((lane >> 4) << 2);
#pragma unroll
        for (int q = 0; q < 4; ++q)
          LP[PREP_F + mykh * 1056 + prow * 33 + pcol + q] = acc[q];
      }
    }

    // out-dot (waves 6-7): 512 tasks = 2 half x 16 bl x 16 ks, 4 per thread
    if (wv >= 6) {
#pragma unroll
      for (int tk = 0; tk < 4; ++tk) {
        const int task = (tid - 384) + tk * 128;
        const int half = task >> 8, rem = task & 255;
        const int bl = rem & 15, ks = rem >> 4;
        const int b = half * 16 + bl;
        const float* woc = &LP[WOC_F];
        float oa = 0.f;
#pragma unroll
        for (int c = 0; c < 4; ++c) {
          const uint4 wh = *(const uint4*)(smem + (size_t)((half * 32 + ks) * 1024) + (bl | (c << 4)) * 16);
          const uint4 wl = *(const uint4*)(smem + (size_t)((half * 32 + 16 + ks) * 1024) + (bl | (c << 4)) * 16);
          int k0 = ks * 32 + c * 8;
          oa = fmaf(bfhilo(wh.x & 0xFFFFu, wl.x & 0xFFFFu), woc[k0 + 0], oa);
          oa = fmaf(bfhilo(wh.x >> 16, wl.x >> 16), woc[k0 + 1], oa);
          oa = fmaf(bfhilo(wh.y & 0xFFFFu, wl.y & 0xFFFFu), woc[k0 + 2], oa);
          oa = fmaf(bfhilo(wh.y >> 16, wl.y >> 16), woc[k0 + 3], oa);
          oa = fmaf(bfhilo(wh.z & 0xFFFFu, wl.z & 0xFFFFu), woc[k0 + 4], oa);
          oa = fmaf(bfhilo(wh.z >> 16, wl.z >> 16), woc[k0 + 5], oa);
          oa = fmaf(bfhilo(wh.w & 0xFFFFu, wl.w & 0xFFFFu), woc[k0 + 6], oa);
          oa = fmaf(bfhilo(wh.w >> 16, wl.w >> 16), woc[k0 + 7], oa);
        }
        LP[ORED_F + b * 17 + ks] = oa;
      }
    }
    __syncthreads();   // sync B

    if (!last) {
      // -------- gates -> shfl pack -> sc1 publish --------
      if (tid < 256) {
        const int b = tid & 31, jj = tid >> 5;
        float pr  = LP[PREP_F + jj * 33 + b]        + LP[PREP_F + 1056 + jj * 33 + b];
        float pz  = LP[PREP_F + (8 + jj) * 33 + b]  + LP[PREP_F + 1056 + (8 + jj) * 33 + b];
        float pnh = LP[PREP_F + (16 + jj) * 33 + b] + LP[PREP_F + 1056 + (16 + jj) * 33 + b]
                  + LP[SB_F + 48 + jj];
        float pni;
        if (teacher) {
          pr += LP[XPRE_F + jj * 33 + b] + LP[SB_F + jj];
          pz += LP[XPRE_F + (8 + jj) * 33 + b] + LP[SB_F + 8 + jj];
          pni = LP[XPRE_F + (16 + jj) * 33 + b] + LP[SB_F + 56 + jj];
        } else {
          float xl = LP[XLAST_F + b];
          pr += LP[SB_F + 16 + jj] + LP[SB_F + 32 + jj] * xl;
          pz += LP[SB_F + 24 + jj] + LP[SB_F + 40 + jj] * xl;
          pni = LP[PREP_F + (24 + jj) * 33 + b] + LP[PREP_F + 1056 + (24 + jj) * 33 + b]
              + LP[SB_F + 64 + jj] + LP[SB_F + 72 + jj] * xl;
        }
        float rg = 1.f / (1.f + expf(-pr));
        float zg = 1.f / (1.f + expf(-pz));
        float ng = tanhf(fmaf(rg, pnh, pni));
        float hv = fmaf(zg, hp - ng, ng);
        float hvp = __shfl_xor(hv, 32, 64);   // partner dim (jj^1), same batch
        if ((jj & 1) == 0) {
          unsigned h0h = rne16(hv), h1h = rne16(hvp);
          float r0 = hv  - __uint_as_float(h0h << 16);
          float r1 = hvp - __uint_as_float(h1h << 16);
          unsigned hw = h0h | (h1h << 16);
          unsigned lw = rne16(r0) | (rne16(r1) << 16);
          char* dst = data + (size_t)(hmode ? (t + 1) : ((t + 1) & 1)) * STEP_BYTES
                    + (size_t)g * GRP_BYTES;
          const int half = b >> 4, ln2 = (b & 15) | ((s & 3) << 4), ks2 = s >> 2;
          unsigned* dhh = (unsigned*)(dst + (size_t)((ks2 * 2 + half) * 64 + ln2) * 16 + jj * 2);
          unsigned* dhl = (unsigned*)(dst + (size_t)(((16 + ks2) * 2 + half) * 64 + ln2) * 16 + jj * 2);
          __hip_atomic_store(dhh, hw, __ATOMIC_RELAXED, __HIP_MEMORY_SCOPE_AGENT);
          __hip_atomic_store(dhl, lw, __ATOMIC_RELAXED, __HIP_MEMORY_SCOPE_AGENT);
        }
      }
      // -------- barrier: drain, arrive (own flag), hidden work, ballot-poll --------
      asm volatile("s_waitcnt vmcnt(0)" ::: "memory");
      __syncthreads();   // sync C: all publishes acked
      const unsigned tgt = (unsigned)(t + 2);
      if (tid == 0)
        __hip_atomic_store(&myflags[s], tgt, __ATOMIC_RELAXED, __HIP_MEMORY_SCOPE_AGENT);
      if (t >= 1 && tid >= 256 && tid < 288) {
        const int b = tid - 256;
        float o = LP[SB_F + 80];
#pragma unroll
        for (int i = 0; i < 16; ++i) o += LP[ORED_F + b * 17 + i];
        out[((size_t)(bg0 + b) * 512 + (t - 1)) * 64 + s] = o;
      }
      stage_x(t + 1);   // h-independent work hidden under the detect window
      if (wv == 0) {
        int cnt = 0;
        while (true) {
          unsigned v = __hip_atomic_load(&myflags[lane], __ATOMIC_RELAXED, __HIP_MEMORY_SCOPE_AGENT);
          if (__ballot(v < tgt) == 0ull) break;
          __builtin_amdgcn_s_sleep(1);
          if (++cnt > 200000) break;   // escape hatch: wrong answer instead of hang
        }
      }
      __syncthreads();   // sync D: release
    } else {
      // t == 512: ORED holds h_arr[511] partials; write the final out row
      if (tid >= 256 && tid < 288) {
        const int b = tid - 256;
        float o = LP[SB_F + 80];
#pragma unroll
        for (int i = 0; i < 16; ++i) o += LP[ORED_F + b * 17 + i];
        out[((size_t)(bg0 + b) * 512 + 511) * 64 + s] = o;
      }
    }
  }
}

extern "C" void kernel_launch(void* const* d_in, const int* in_sizes, int n_in,
                              void* d_out, int out_size, void* d_ws, size_t ws_size,
                              hipStream_t stream) {
  (void)in_sizes; (void)n_in; (void)out_size;
  const float* x    = (const float*)d_in[0];
  const float* tp   = (const float*)d_in[1];
  const int*   mask = (const int*)d_in[2];
  const float* W_ih = (const float*)d_in[3];
  const float* W_hh = (const float*)d_in[4];
  const float* b_ih = (const float*)d_in[5];
  const float* b_hh = (const float*)d_in[6];
  const float* W_out= (const float*)d_in[7];
  const float* b_out= (const float*)d_in[8];
  float* out = (float*)d_out;
  if (ws_size < FB_NEEDED) return;
  int hmode = (ws_size >= HIST_NEEDED) ? 1 : 0;
  unsigned* flags = (unsigned*)d_ws;
  char* dataptr = (char*)d_ws + 4096;
  hipMemsetAsync(flags, 0, 4096, stream);
  hipFuncSetAttribute((const void*)gru_persistent,
                      hipFuncAttributeMaxDynamicSharedMemorySize, LDS_BYTES);
  hipLaunchKernelGGL(gru_persistent, dim3(256), dim3(TB), LDS_BYTES, stream,
                     x, tp, mask, W_ih, W_hh, b_ih, b_hh, W_out, b_out, dataptr, flags, out, hmode);
}